// Round 1
// baseline (1456.903 us; speedup 1.0000x reference)
//
#include <hip/hip_runtime.h>

#define NN 50000
#define NE 800000
#define NG 128
#define HD 128
#define NL 4
#define BN_EPS 1e-5f

// ---------------- embed: x[n] = node_emb[x_ids[n]] ----------------
__global__ __launch_bounds__(256) void embed_kernel(const int* __restrict__ ids,
                                                    const float* __restrict__ emb,
                                                    float* __restrict__ x) {
    int i = blockIdx.x * 256 + threadIdx.x;      // over NN*32 float4 groups
    if (i < NN * 32) {
        int node = i >> 5, q = i & 31;
        int id = ids[node];
        float4 v = *(const float4*)(emb + (size_t)id * HD + 4 * q);
        *(float4*)(x + (size_t)node * HD + 4 * q) = v;
    }
}

// ---------------- CSR build ----------------
__global__ __launch_bounds__(256) void hist_kernel(const int* __restrict__ dst,
                                                   int* __restrict__ deg) {
    int e = blockIdx.x * 256 + threadIdx.x;
    if (e < NE) atomicAdd(&deg[dst[e]], 1);
}

__global__ __launch_bounds__(1024) void scan_kernel(const int* __restrict__ deg,
                                                    int* __restrict__ rowptr,
                                                    int* __restrict__ cursor) {
    __shared__ int ssum[1024];
    int t = threadIdx.x;
    const int ch = (NN + 1023) >> 10;  // 49
    int start = t * ch;
    int s = 0;
    for (int i = 0; i < ch; i++) {
        int ix = start + i;
        if (ix < NN) s += deg[ix];
    }
    ssum[t] = s;
    __syncthreads();
    for (int off = 1; off < 1024; off <<= 1) {
        int v = (t >= off) ? ssum[t - off] : 0;
        __syncthreads();
        ssum[t] += v;
        __syncthreads();
    }
    int run = ssum[t] - s;  // exclusive
    for (int i = 0; i < ch; i++) {
        int ix = start + i;
        if (ix < NN) {
            rowptr[ix] = run;
            cursor[ix] = run;
            run += deg[ix];
        }
    }
    if (t == 1023) rowptr[NN] = ssum[1023];
}

__global__ __launch_bounds__(256) void scatter_kernel(const int* __restrict__ src,
                                                      const int* __restrict__ dst,
                                                      const int* __restrict__ attr,
                                                      int* __restrict__ cursor,
                                                      unsigned* __restrict__ csr) {
    int e = blockIdx.x * 256 + threadIdx.x;
    if (e < NE) {
        int d = dst[e];
        int pos = atomicAdd(&cursor[d], 1);
        csr[pos] = (unsigned)src[e] | ((unsigned)attr[e] << 16);  // src < 65536, attr < 8
    }
}

// ---------------- GINE conv: out[n] = (1+eps)*act(x[n]) + sum_{e->n} relu(act(x[src])+e_emb) ----------------
__global__ __launch_bounds__(256) void conv_kernel(const float* __restrict__ x,
                                                   const int* __restrict__ rowptr,
                                                   const unsigned* __restrict__ csr,
                                                   const float* __restrict__ edge_emb,
                                                   const float* __restrict__ eps, int layer,
                                                   const float* __restrict__ sc,
                                                   const float* __restrict__ sh, int apply_act,
                                                   float* __restrict__ out) {
    __shared__ float elds[8 * HD];
    int t = threadIdx.x;
    ((float4*)elds)[t] = ((const float4*)edge_emb)[t];  // 256*16B = 4KB
    __syncthreads();
    int wave = t >> 6, lane = t & 63;
    int node = blockIdx.x * 4 + wave;
    if (node >= NN) return;
    int lo = rowptr[node], hi = rowptr[node + 1];
    float sc0 = 1.f, sc1 = 1.f, sh0 = 0.f, sh1 = 0.f;
    if (apply_act) {
        sc0 = sc[2 * lane]; sc1 = sc[2 * lane + 1];
        sh0 = sh[2 * lane]; sh1 = sh[2 * lane + 1];
    }
    float a0 = 0.f, a1 = 0.f;
    for (int base = lo; base < hi; base += 64) {
        unsigned pl = 0;
        int cnt = hi - base; if (cnt > 64) cnt = 64;
        if (base + lane < hi) pl = csr[base + lane];
        for (int j = 0; j < cnt; j++) {
            unsigned p = __shfl(pl, j, 64);
            int s = p & 0xFFFF;
            int a = p >> 16;
            float2 xv = *(const float2*)(x + (size_t)s * HD + 2 * lane);
            float vx0 = xv.x, vx1 = xv.y;
            if (apply_act) {
                vx0 = fmaxf(fmaf(vx0, sc0, sh0), 0.f);
                vx1 = fmaxf(fmaf(vx1, sc1, sh1), 0.f);
            }
            float e0 = elds[a * HD + 2 * lane], e1 = elds[a * HD + 2 * lane + 1];
            a0 += fmaxf(vx0 + e0, 0.f);
            a1 += fmaxf(vx1 + e1, 0.f);
        }
    }
    float ep = eps[layer];
    float2 xs = *(const float2*)(x + (size_t)node * HD + 2 * lane);
    float x0 = xs.x, x1 = xs.y;
    if (apply_act) {
        x0 = fmaxf(fmaf(x0, sc0, sh0), 0.f);
        x1 = fmaxf(fmaf(x1, sc1, sh1), 0.f);
    }
    float2 o;
    o.x = (1.f + ep) * x0 + a0;
    o.y = (1.f + ep) * x1 + a1;
    *(float2*)(out + (size_t)node * HD + 2 * lane) = o;
}

// ---------------- matmul: out = act_in(A) @ W (+bias); accumulate col sum/sumsq ----------------
__global__ __launch_bounds__(256) void mm_kernel(const float* __restrict__ A,
                                                 const float* __restrict__ W,
                                                 const float* __restrict__ bias,
                                                 const float* __restrict__ sc_in,
                                                 const float* __restrict__ sh_in,
                                                 float* __restrict__ out, int nrows,
                                                 float* __restrict__ stats_s,
                                                 float* __restrict__ stats_q) {
    const int PADK = 132;
    __shared__ float As[64 * PADK];
    __shared__ float colS[HD], colQ[HD];
    int t = threadIdx.x;
    if (t < HD) { colS[t] = 0.f; colQ[t] = 0.f; }
    int row0 = blockIdx.x * 64;
#pragma unroll
    for (int i = 0; i < 8; i++) {
        int idx = t + i * 256;  // 0..2047
        int r = idx >> 5, kq = idx & 31;
        float4 v = make_float4(0.f, 0.f, 0.f, 0.f);
        int gr = row0 + r;
        if (gr < nrows) v = *(const float4*)(A + (size_t)gr * HD + 4 * kq);
        if (sc_in) {
            float4 s4 = *(const float4*)(sc_in + 4 * kq);
            float4 h4 = *(const float4*)(sh_in + 4 * kq);
            v.x = fmaxf(fmaf(v.x, s4.x, h4.x), 0.f);
            v.y = fmaxf(fmaf(v.y, s4.y, h4.y), 0.f);
            v.z = fmaxf(fmaf(v.z, s4.z, h4.z), 0.f);
            v.w = fmaxf(fmaf(v.w, s4.w, h4.w), 0.f);
        }
        *(float4*)&As[r * PADK + 4 * kq] = v;
    }
    __syncthreads();
    int jq = t & 31, rb = t >> 5;
    float acc[8][4];
#pragma unroll
    for (int i = 0; i < 8; i++)
#pragma unroll
        for (int j = 0; j < 4; j++) acc[i][j] = 0.f;
    const float* Wp = W + 4 * jq;
    const float* Ap = &As[rb * 8 * PADK];
    for (int k = 0; k < HD; k++) {
        float4 w4 = *(const float4*)(Wp + (size_t)k * HD);
#pragma unroll
        for (int i = 0; i < 8; i++) {
            float a = Ap[i * PADK + k];
            acc[i][0] = fmaf(a, w4.x, acc[i][0]);
            acc[i][1] = fmaf(a, w4.y, acc[i][1]);
            acc[i][2] = fmaf(a, w4.z, acc[i][2]);
            acc[i][3] = fmaf(a, w4.w, acc[i][3]);
        }
    }
    float4 b4 = make_float4(0.f, 0.f, 0.f, 0.f);
    if (bias) b4 = *(const float4*)(bias + 4 * jq);
    float s0 = 0, s1 = 0, s2 = 0, s3 = 0, q0 = 0, q1 = 0, q2 = 0, q3 = 0;
#pragma unroll
    for (int i = 0; i < 8; i++) {
        int gr = row0 + rb * 8 + i;
        if (gr < nrows) {
            float4 v;
            v.x = acc[i][0] + b4.x;
            v.y = acc[i][1] + b4.y;
            v.z = acc[i][2] + b4.z;
            v.w = acc[i][3] + b4.w;
            *(float4*)(out + (size_t)gr * HD + 4 * jq) = v;
            s0 += v.x; q0 += v.x * v.x;
            s1 += v.y; q1 += v.y * v.y;
            s2 += v.z; q2 += v.z * v.z;
            s3 += v.w; q3 += v.w * v.w;
        }
    }
    atomicAdd(&colS[4 * jq + 0], s0); atomicAdd(&colQ[4 * jq + 0], q0);
    atomicAdd(&colS[4 * jq + 1], s1); atomicAdd(&colQ[4 * jq + 1], q1);
    atomicAdd(&colS[4 * jq + 2], s2); atomicAdd(&colQ[4 * jq + 2], q2);
    atomicAdd(&colS[4 * jq + 3], s3); atomicAdd(&colQ[4 * jq + 3], q3);
    __syncthreads();
    if (t < HD) {
        atomicAdd(&stats_s[t], colS[t]);
        atomicAdd(&stats_q[t], colQ[t]);
    }
}

// ---------------- BN stats -> (scale, shift); zero stats for next use ----------------
__global__ __launch_bounds__(128) void finalize_kernel(float* __restrict__ ss, float* __restrict__ sq,
                                                       const float* __restrict__ gam,
                                                       const float* __restrict__ bet, float inv_cnt,
                                                       float* __restrict__ sc, float* __restrict__ sh) {
    int t = threadIdx.x;  // 128
    float s = ss[t], q = sq[t];
    float m = s * inv_cnt;
    float v = fmaf(q, inv_cnt, -m * m);
    v = fmaxf(v, 0.f);
    float inv = rsqrtf(v + BN_EPS);
    float scale = gam[t] * inv;
    sc[t] = scale;
    sh[t] = fmaf(-m, scale, bet[t]);
    ss[t] = 0.f;
    sq[t] = 0.f;
}

__device__ int lower_bound_i(const int* a, int n, int key) {
    int lo = 0, hi = n;
    while (lo < hi) {
        int mid = (lo + hi) >> 1;
        if (a[mid] < key) lo = mid + 1;
        else hi = mid;
    }
    return lo;
}

// ---------------- readout: g[b] = sum over nodes of act(x) ----------------
__global__ __launch_bounds__(128) void readout_kernel(const float* __restrict__ x,
                                                      const int* __restrict__ batch,
                                                      const float* __restrict__ sc,
                                                      const float* __restrict__ sh,
                                                      float* __restrict__ gout) {
    int g = blockIdx.x;
    int t = threadIdx.x;  // 128 = channel
    int lo = lower_bound_i(batch, NN, g);
    int hi = lower_bound_i(batch, NN, g + 1);
    float scv = sc[t], shv = sh[t];
    float s = 0.f;
    for (int r = lo; r < hi; r++) {
        float v = x[(size_t)r * HD + t];
        s += fmaxf(fmaf(v, scv, shv), 0.f);
    }
    gout[(size_t)g * HD + t] = s;
}

// ---------------- final: out[g] = act(h[g]) . fin_W ----------------
__global__ __launch_bounds__(128) void final_kernel(const float* __restrict__ h,
                                                    const float* __restrict__ sc,
                                                    const float* __restrict__ sh,
                                                    const float* __restrict__ finW,
                                                    float* __restrict__ out) {
    int t = threadIdx.x;  // 128 = graph
    float s = 0.f;
    for (int c = 0; c < HD; c++) {
        float v = h[(size_t)t * HD + c];
        v = fmaxf(fmaf(v, sc[c], sh[c]), 0.f);
        s += v * finW[c];
    }
    out[t] = s;
}

extern "C" void kernel_launch(void* const* d_in, const int* in_sizes, int n_in,
                              void* d_out, int out_size, void* d_ws, size_t ws_size,
                              hipStream_t stream) {
    const int* x_ids = (const int*)d_in[0];
    const int* edge_index = (const int*)d_in[1];
    const int* batch = (const int*)d_in[2];
    const int* edge_attr = (const int*)d_in[3];
    const float* node_emb = (const float*)d_in[4];
    const float* edge_emb = (const float*)d_in[5];
    const float* eps = (const float*)d_in[6];
    const float* init_W1 = (const float*)d_in[7];
    const float* init_b1 = (const float*)d_in[8];
    const float* init_g1 = (const float*)d_in[9];
    const float* init_be1 = (const float*)d_in[10];
    const float* init_W2 = (const float*)d_in[11];
    const float* init_b2 = (const float*)d_in[12];
    const float* init_g2 = (const float*)d_in[13];
    const float* init_be2 = (const float*)d_in[14];
    const float* mp_W1 = (const float*)d_in[15];
    const float* mp_g1 = (const float*)d_in[16];
    const float* mp_be1 = (const float*)d_in[17];
    const float* mp_W2 = (const float*)d_in[18];
    const float* mp_g2 = (const float*)d_in[19];
    const float* mp_be2 = (const float*)d_in[20];
    const float* l1_W1 = (const float*)d_in[21];
    const float* l1_g1 = (const float*)d_in[22];
    const float* l1_b1 = (const float*)d_in[23];
    const float* l1_W2 = (const float*)d_in[24];
    const float* l1_g2 = (const float*)d_in[25];
    const float* l1_b2 = (const float*)d_in[26];
    const float* l2_W1 = (const float*)d_in[27];
    const float* l2_g1 = (const float*)d_in[28];
    const float* l2_b1 = (const float*)d_in[29];
    const float* l2_W2 = (const float*)d_in[30];
    const float* l2_g2 = (const float*)d_in[31];
    const float* l2_b2 = (const float*)d_in[32];
    const float* fin_W = (const float*)d_in[33];

    const int* e_src = edge_index;
    const int* e_dst = edge_index + NE;

    // workspace layout (floats)
    float* ws = (float*)d_ws;
    float* X = ws;                       // 50000*128
    float* Abuf = X + (size_t)NN * HD;   // 50000*128
    float* Bbuf = Abuf + (size_t)NN * HD;
    float* Gp = Bbuf + (size_t)NN * HD;  // 128*128
    float* S1 = Gp + NG * HD;            // 128
    float* Q1 = S1 + HD;                 // 128
    float* scA = Q1 + HD;
    float* shA = scA + HD;
    float* scB = shA + HD;
    float* shB = scB + HD;
    int* rowptr = (int*)(shB + HD);      // 50001 -> pad 50048
    int* cursor = rowptr + 50048;
    int* deg = cursor + 50048;
    unsigned* csr = (unsigned*)(deg + 50048);  // 800000

    hipMemsetAsync(deg, 0, NN * sizeof(int), stream);
    hipMemsetAsync(S1, 0, 2 * HD * sizeof(float), stream);

    embed_kernel<<<(NN * 32) / 256, 256, 0, stream>>>(x_ids, node_emb, X);
    hist_kernel<<<(NE + 255) / 256, 256, 0, stream>>>(e_dst, deg);
    scan_kernel<<<1, 1024, 0, stream>>>(deg, rowptr, cursor);
    scatter_kernel<<<(NE + 255) / 256, 256, 0, stream>>>(e_src, e_dst, edge_attr, cursor, csr);

    const int mm_grid = (NN + 63) / 64;  // 782
    for (int i = 0; i <= NL; i++) {
        const float *W1, *b1, *g1, *be1, *W2, *b2, *g2, *be2;
        if (i == 0) {
            W1 = init_W1; b1 = init_b1; g1 = init_g1; be1 = init_be1;
            W2 = init_W2; b2 = init_b2; g2 = init_g2; be2 = init_be2;
        } else {
            W1 = mp_W1 + (size_t)(i - 1) * HD * HD; b1 = nullptr;
            g1 = mp_g1 + (size_t)(i - 1) * HD; be1 = mp_be1 + (size_t)(i - 1) * HD;
            W2 = mp_W2 + (size_t)(i - 1) * HD * HD; b2 = nullptr;
            g2 = mp_g2 + (size_t)(i - 1) * HD; be2 = mp_be2 + (size_t)(i - 1) * HD;
        }
        conv_kernel<<<(NN + 3) / 4, 256, 0, stream>>>(X, rowptr, csr, edge_emb, eps, i, scB,
                                                      shB, (i > 0) ? 1 : 0, Abuf);
        mm_kernel<<<mm_grid, 256, 0, stream>>>(Abuf, W1, b1, nullptr, nullptr, Bbuf, NN, S1, Q1);
        finalize_kernel<<<1, 128, 0, stream>>>(S1, Q1, g1, be1, 1.f / NN, scA, shA);
        mm_kernel<<<mm_grid, 256, 0, stream>>>(Bbuf, W2, b2, scA, shA, X, NN, S1, Q1);
        finalize_kernel<<<1, 128, 0, stream>>>(S1, Q1, g2, be2, 1.f / NN, scB, shB);
    }

    readout_kernel<<<NG, 128, 0, stream>>>(X, batch, scB, shB, Gp);

    // head: 4x (mm + finalize), count = 128
    mm_kernel<<<2, 256, 0, stream>>>(Gp, l1_W1, nullptr, nullptr, nullptr, Abuf, NG, S1, Q1);
    finalize_kernel<<<1, 128, 0, stream>>>(S1, Q1, l1_g1, l1_b1, 1.f / NG, scA, shA);
    mm_kernel<<<2, 256, 0, stream>>>(Abuf, l1_W2, nullptr, scA, shA, Bbuf, NG, S1, Q1);
    finalize_kernel<<<1, 128, 0, stream>>>(S1, Q1, l1_g2, l1_b2, 1.f / NG, scB, shB);
    mm_kernel<<<2, 256, 0, stream>>>(Bbuf, l2_W1, nullptr, scB, shB, Abuf, NG, S1, Q1);
    finalize_kernel<<<1, 128, 0, stream>>>(S1, Q1, l2_g1, l2_b1, 1.f / NG, scA, shA);
    mm_kernel<<<2, 256, 0, stream>>>(Abuf, l2_W2, nullptr, scA, shA, Bbuf, NG, S1, Q1);
    finalize_kernel<<<1, 128, 0, stream>>>(S1, Q1, l2_g2, l2_b2, 1.f / NG, scB, shB);

    final_kernel<<<1, 128, 0, stream>>>(Bbuf, scB, shB, fin_W, (float*)d_out);
}

// Round 2
// 1283.779 us; speedup vs baseline: 1.1349x; 1.1349x over previous
//
#include <hip/hip_runtime.h>

#define NN 50000
#define NE 800000
#define NG 128
#define HD 128
#define NL 4
#define BN_EPS 1e-5f

// ---------------- embed: x[n] = node_emb[x_ids[n]] ----------------
__global__ __launch_bounds__(256) void embed_kernel(const int* __restrict__ ids,
                                                    const float* __restrict__ emb,
                                                    float* __restrict__ x) {
    int i = blockIdx.x * 256 + threadIdx.x;      // over NN*32 float4 groups
    if (i < NN * 32) {
        int node = i >> 5, q = i & 31;
        int id = ids[node];
        float4 v = *(const float4*)(emb + (size_t)id * HD + 4 * q);
        *(float4*)(x + (size_t)node * HD + 4 * q) = v;
    }
}

// ---------------- CSR build ----------------
__global__ __launch_bounds__(256) void hist_kernel(const int* __restrict__ dst,
                                                   int* __restrict__ deg) {
    int e = blockIdx.x * 256 + threadIdx.x;
    if (e < NE) atomicAdd(&deg[dst[e]], 1);
}

// block-local inclusive scan -> rowptr holds local-exclusive, blockSum[b] = block total
__global__ __launch_bounds__(1024) void scan1_kernel(const int* __restrict__ deg,
                                                     int* __restrict__ rowptr,
                                                     int* __restrict__ blockSum) {
    __shared__ int s[1024];
    int b = blockIdx.x, t = threadIdx.x;
    int i = b * 1024 + t;
    int v = (i < NN) ? deg[i] : 0;
    s[t] = v;
    __syncthreads();
    for (int off = 1; off < 1024; off <<= 1) {
        int u = (t >= off) ? s[t - off] : 0;
        __syncthreads();
        s[t] += u;
        __syncthreads();
    }
    if (i < NN) rowptr[i] = s[t] - v;  // local exclusive
    if (t == 1023) blockSum[b] = s[1023];
}

// scan 49 block sums -> exclusive blockOff; write rowptr[NN]=total
__global__ __launch_bounds__(64) void scan2_kernel(const int* __restrict__ blockSum,
                                                   int* __restrict__ blockOff,
                                                   int* __restrict__ rowptr, int nblocks) {
    int t = threadIdx.x;
    int orig = (t < nblocks) ? blockSum[t] : 0;
    int v = orig;
    for (int off = 1; off < 64; off <<= 1) {
        int u = __shfl_up(v, off, 64);
        if (t >= off) v += u;
    }
    if (t < nblocks) blockOff[t] = v - orig;
    if (t == nblocks - 1) rowptr[NN] = v;
}

__global__ __launch_bounds__(1024) void scan3_kernel(int* __restrict__ rowptr,
                                                     int* __restrict__ cursor,
                                                     const int* __restrict__ blockOff) {
    int b = blockIdx.x, t = threadIdx.x;
    int i = b * 1024 + t;
    if (i < NN) {
        int r = rowptr[i] + blockOff[b];
        rowptr[i] = r;
        cursor[i] = r;
    }
}

__global__ __launch_bounds__(256) void scatter_kernel(const int* __restrict__ src,
                                                      const int* __restrict__ dst,
                                                      const int* __restrict__ attr,
                                                      int* __restrict__ cursor,
                                                      unsigned* __restrict__ csr) {
    int e = blockIdx.x * 256 + threadIdx.x;
    if (e < NE) {
        int d = dst[e];
        int pos = atomicAdd(&cursor[d], 1);
        csr[pos] = (unsigned)src[e] | ((unsigned)attr[e] << 16);  // src < 65536, attr < 8
    }
}

// ---------------- GINE conv: out[n] = (1+eps)*act(x[n]) + sum_{e->n} relu(act(x[src])+e_emb) ----------------
__global__ __launch_bounds__(256) void conv_kernel(const float* __restrict__ x,
                                                   const int* __restrict__ rowptr,
                                                   const unsigned* __restrict__ csr,
                                                   const float* __restrict__ edge_emb,
                                                   const float* __restrict__ eps, int layer,
                                                   const float* __restrict__ sc,
                                                   const float* __restrict__ sh, int apply_act,
                                                   float* __restrict__ out) {
    __shared__ float elds[8 * HD];
    int t = threadIdx.x;
    ((float4*)elds)[t] = ((const float4*)edge_emb)[t];  // 256*16B = 4KB
    __syncthreads();
    int wave = t >> 6, lane = t & 63;
    int node = blockIdx.x * 4 + wave;
    if (node >= NN) return;
    int lo = rowptr[node], hi = rowptr[node + 1];
    float sc0 = 1.f, sc1 = 1.f, sh0 = 0.f, sh1 = 0.f;
    if (apply_act) {
        sc0 = sc[2 * lane]; sc1 = sc[2 * lane + 1];
        sh0 = sh[2 * lane]; sh1 = sh[2 * lane + 1];
    }
    float a0 = 0.f, a1 = 0.f;
    for (int base = lo; base < hi; base += 64) {
        unsigned pl = 0;
        int cnt = hi - base; if (cnt > 64) cnt = 64;
        if (base + lane < hi) pl = csr[base + lane];
        int j = 0;
        for (; j + 2 <= cnt; j += 2) {
            unsigned p0 = __shfl(pl, j, 64);
            unsigned p1 = __shfl(pl, j + 1, 64);
            float2 xv0 = *(const float2*)(x + (size_t)(p0 & 0xFFFFu) * HD + 2 * lane);
            float2 xv1 = *(const float2*)(x + (size_t)(p1 & 0xFFFFu) * HD + 2 * lane);
            float u0 = xv0.x, u1 = xv0.y, w0 = xv1.x, w1 = xv1.y;
            if (apply_act) {
                u0 = fmaxf(fmaf(u0, sc0, sh0), 0.f);
                u1 = fmaxf(fmaf(u1, sc1, sh1), 0.f);
                w0 = fmaxf(fmaf(w0, sc0, sh0), 0.f);
                w1 = fmaxf(fmaf(w1, sc1, sh1), 0.f);
            }
            int ea0 = p0 >> 16, ea1 = p1 >> 16;
            a0 += fmaxf(u0 + elds[ea0 * HD + 2 * lane], 0.f);
            a1 += fmaxf(u1 + elds[ea0 * HD + 2 * lane + 1], 0.f);
            a0 += fmaxf(w0 + elds[ea1 * HD + 2 * lane], 0.f);
            a1 += fmaxf(w1 + elds[ea1 * HD + 2 * lane + 1], 0.f);
        }
        if (j < cnt) {
            unsigned p = __shfl(pl, j, 64);
            int s = p & 0xFFFF;
            int a = p >> 16;
            float2 xv = *(const float2*)(x + (size_t)s * HD + 2 * lane);
            float vx0 = xv.x, vx1 = xv.y;
            if (apply_act) {
                vx0 = fmaxf(fmaf(vx0, sc0, sh0), 0.f);
                vx1 = fmaxf(fmaf(vx1, sc1, sh1), 0.f);
            }
            a0 += fmaxf(vx0 + elds[a * HD + 2 * lane], 0.f);
            a1 += fmaxf(vx1 + elds[a * HD + 2 * lane + 1], 0.f);
        }
    }
    float ep = eps[layer];
    float2 xs = *(const float2*)(x + (size_t)node * HD + 2 * lane);
    float x0 = xs.x, x1 = xs.y;
    if (apply_act) {
        x0 = fmaxf(fmaf(x0, sc0, sh0), 0.f);
        x1 = fmaxf(fmaf(x1, sc1, sh1), 0.f);
    }
    float2 o;
    o.x = (1.f + ep) * x0 + a0;
    o.y = (1.f + ep) * x1 + a1;
    *(float2*)(out + (size_t)node * HD + 2 * lane) = o;
}

// ---------------- matmul: out = act_in(A) @ W (+bias); accumulate col sum/sumsq ----------------
__global__ __launch_bounds__(256) void mm_kernel(const float* __restrict__ A,
                                                 const float* __restrict__ W,
                                                 const float* __restrict__ bias,
                                                 const float* __restrict__ sc_in,
                                                 const float* __restrict__ sh_in,
                                                 float* __restrict__ out, int nrows,
                                                 float* __restrict__ stats_s,
                                                 float* __restrict__ stats_q) {
    const int PADK = 132;  // stride in dwords: %32==4 -> distinct banks across i; 16B-aligned rows
    __shared__ float As[64 * PADK];
    __shared__ float colS[HD], colQ[HD];
    int t = threadIdx.x;
    if (t < HD) { colS[t] = 0.f; colQ[t] = 0.f; }
    int row0 = blockIdx.x * 64;
#pragma unroll
    for (int i = 0; i < 8; i++) {
        int idx = t + i * 256;  // 0..2047
        int r = idx >> 5, kq = idx & 31;
        float4 v = make_float4(0.f, 0.f, 0.f, 0.f);
        int gr = row0 + r;
        if (gr < nrows) v = *(const float4*)(A + (size_t)gr * HD + 4 * kq);
        if (sc_in) {
            float4 s4 = *(const float4*)(sc_in + 4 * kq);
            float4 h4 = *(const float4*)(sh_in + 4 * kq);
            v.x = fmaxf(fmaf(v.x, s4.x, h4.x), 0.f);
            v.y = fmaxf(fmaf(v.y, s4.y, h4.y), 0.f);
            v.z = fmaxf(fmaf(v.z, s4.z, h4.z), 0.f);
            v.w = fmaxf(fmaf(v.w, s4.w, h4.w), 0.f);
        }
        *(float4*)&As[r * PADK + 4 * kq] = v;
    }
    __syncthreads();
    int jq = t & 31, rb = t >> 5;
    float acc[8][4];
#pragma unroll
    for (int i = 0; i < 8; i++)
#pragma unroll
        for (int j = 0; j < 4; j++) acc[i][j] = 0.f;
    const float* Wp = W + 4 * jq;
    const float* Ap = &As[rb * 8 * PADK];
    for (int k = 0; k < HD; k += 4) {
        float4 w0 = *(const float4*)(Wp + (size_t)(k + 0) * HD);
        float4 w1 = *(const float4*)(Wp + (size_t)(k + 1) * HD);
        float4 w2 = *(const float4*)(Wp + (size_t)(k + 2) * HD);
        float4 w3 = *(const float4*)(Wp + (size_t)(k + 3) * HD);
#pragma unroll
        for (int i = 0; i < 8; i++) {
            float4 a4 = *(const float4*)&Ap[i * PADK + k];
            acc[i][0] = fmaf(a4.x, w0.x, acc[i][0]);
            acc[i][1] = fmaf(a4.x, w0.y, acc[i][1]);
            acc[i][2] = fmaf(a4.x, w0.z, acc[i][2]);
            acc[i][3] = fmaf(a4.x, w0.w, acc[i][3]);
            acc[i][0] = fmaf(a4.y, w1.x, acc[i][0]);
            acc[i][1] = fmaf(a4.y, w1.y, acc[i][1]);
            acc[i][2] = fmaf(a4.y, w1.z, acc[i][2]);
            acc[i][3] = fmaf(a4.y, w1.w, acc[i][3]);
            acc[i][0] = fmaf(a4.z, w2.x, acc[i][0]);
            acc[i][1] = fmaf(a4.z, w2.y, acc[i][1]);
            acc[i][2] = fmaf(a4.z, w2.z, acc[i][2]);
            acc[i][3] = fmaf(a4.z, w2.w, acc[i][3]);
            acc[i][0] = fmaf(a4.w, w3.x, acc[i][0]);
            acc[i][1] = fmaf(a4.w, w3.y, acc[i][1]);
            acc[i][2] = fmaf(a4.w, w3.z, acc[i][2]);
            acc[i][3] = fmaf(a4.w, w3.w, acc[i][3]);
        }
    }
    float4 b4 = make_float4(0.f, 0.f, 0.f, 0.f);
    if (bias) b4 = *(const float4*)(bias + 4 * jq);
    float s0 = 0, s1 = 0, s2 = 0, s3 = 0, q0 = 0, q1 = 0, q2 = 0, q3 = 0;
#pragma unroll
    for (int i = 0; i < 8; i++) {
        int gr = row0 + rb * 8 + i;
        if (gr < nrows) {
            float4 v;
            v.x = acc[i][0] + b4.x;
            v.y = acc[i][1] + b4.y;
            v.z = acc[i][2] + b4.z;
            v.w = acc[i][3] + b4.w;
            *(float4*)(out + (size_t)gr * HD + 4 * jq) = v;
            s0 += v.x; q0 += v.x * v.x;
            s1 += v.y; q1 += v.y * v.y;
            s2 += v.z; q2 += v.z * v.z;
            s3 += v.w; q3 += v.w * v.w;
        }
    }
    atomicAdd(&colS[4 * jq + 0], s0); atomicAdd(&colQ[4 * jq + 0], q0);
    atomicAdd(&colS[4 * jq + 1], s1); atomicAdd(&colQ[4 * jq + 1], q1);
    atomicAdd(&colS[4 * jq + 2], s2); atomicAdd(&colQ[4 * jq + 2], q2);
    atomicAdd(&colS[4 * jq + 3], s3); atomicAdd(&colQ[4 * jq + 3], q3);
    __syncthreads();
    if (t < HD) {
        atomicAdd(&stats_s[t], colS[t]);
        atomicAdd(&stats_q[t], colQ[t]);
    }
}

// ---------------- BN stats -> (scale, shift); zero stats for next use ----------------
__global__ __launch_bounds__(128) void finalize_kernel(float* __restrict__ ss, float* __restrict__ sq,
                                                       const float* __restrict__ gam,
                                                       const float* __restrict__ bet, float inv_cnt,
                                                       float* __restrict__ sc, float* __restrict__ sh) {
    int t = threadIdx.x;  // 128
    float s = ss[t], q = sq[t];
    float m = s * inv_cnt;
    float v = fmaf(q, inv_cnt, -m * m);
    v = fmaxf(v, 0.f);
    float inv = rsqrtf(v + BN_EPS);
    float scale = gam[t] * inv;
    sc[t] = scale;
    sh[t] = fmaf(-m, scale, bet[t]);
    ss[t] = 0.f;
    sq[t] = 0.f;
}

__device__ int lower_bound_i(const int* a, int n, int key) {
    int lo = 0, hi = n;
    while (lo < hi) {
        int mid = (lo + hi) >> 1;
        if (a[mid] < key) lo = mid + 1;
        else hi = mid;
    }
    return lo;
}

// ---------------- readout: g[b] = sum over nodes of act(x) ----------------
__global__ __launch_bounds__(128) void readout_kernel(const float* __restrict__ x,
                                                      const int* __restrict__ batch,
                                                      const float* __restrict__ sc,
                                                      const float* __restrict__ sh,
                                                      float* __restrict__ gout) {
    int g = blockIdx.x;
    int t = threadIdx.x;  // 128 = channel
    int lo = lower_bound_i(batch, NN, g);
    int hi = lower_bound_i(batch, NN, g + 1);
    float scv = sc[t], shv = sh[t];
    float s = 0.f;
    for (int r = lo; r < hi; r++) {
        float v = x[(size_t)r * HD + t];
        s += fmaxf(fmaf(v, scv, shv), 0.f);
    }
    gout[(size_t)g * HD + t] = s;
}

// ---------------- final: out[g] = act(h[g]) . fin_W ----------------
__global__ __launch_bounds__(128) void final_kernel(const float* __restrict__ h,
                                                    const float* __restrict__ sc,
                                                    const float* __restrict__ sh,
                                                    const float* __restrict__ finW,
                                                    float* __restrict__ out) {
    int t = threadIdx.x;  // 128 = graph
    float s = 0.f;
    for (int c = 0; c < HD; c++) {
        float v = h[(size_t)t * HD + c];
        v = fmaxf(fmaf(v, sc[c], sh[c]), 0.f);
        s += v * finW[c];
    }
    out[t] = s;
}

extern "C" void kernel_launch(void* const* d_in, const int* in_sizes, int n_in,
                              void* d_out, int out_size, void* d_ws, size_t ws_size,
                              hipStream_t stream) {
    const int* x_ids = (const int*)d_in[0];
    const int* edge_index = (const int*)d_in[1];
    const int* batch = (const int*)d_in[2];
    const int* edge_attr = (const int*)d_in[3];
    const float* node_emb = (const float*)d_in[4];
    const float* edge_emb = (const float*)d_in[5];
    const float* eps = (const float*)d_in[6];
    const float* init_W1 = (const float*)d_in[7];
    const float* init_b1 = (const float*)d_in[8];
    const float* init_g1 = (const float*)d_in[9];
    const float* init_be1 = (const float*)d_in[10];
    const float* init_W2 = (const float*)d_in[11];
    const float* init_b2 = (const float*)d_in[12];
    const float* init_g2 = (const float*)d_in[13];
    const float* init_be2 = (const float*)d_in[14];
    const float* mp_W1 = (const float*)d_in[15];
    const float* mp_g1 = (const float*)d_in[16];
    const float* mp_be1 = (const float*)d_in[17];
    const float* mp_W2 = (const float*)d_in[18];
    const float* mp_g2 = (const float*)d_in[19];
    const float* mp_be2 = (const float*)d_in[20];
    const float* l1_W1 = (const float*)d_in[21];
    const float* l1_g1 = (const float*)d_in[22];
    const float* l1_b1 = (const float*)d_in[23];
    const float* l1_W2 = (const float*)d_in[24];
    const float* l1_g2 = (const float*)d_in[25];
    const float* l1_b2 = (const float*)d_in[26];
    const float* l2_W1 = (const float*)d_in[27];
    const float* l2_g1 = (const float*)d_in[28];
    const float* l2_b1 = (const float*)d_in[29];
    const float* l2_W2 = (const float*)d_in[30];
    const float* l2_g2 = (const float*)d_in[31];
    const float* l2_b2 = (const float*)d_in[32];
    const float* fin_W = (const float*)d_in[33];

    const int* e_src = edge_index;
    const int* e_dst = edge_index + NE;

    // workspace layout (floats)
    float* ws = (float*)d_ws;
    float* X = ws;                       // 50000*128
    float* Abuf = X + (size_t)NN * HD;   // 50000*128
    float* Bbuf = Abuf + (size_t)NN * HD;
    float* Gp = Bbuf + (size_t)NN * HD;  // 128*128
    float* S1 = Gp + NG * HD;            // 128
    float* Q1 = S1 + HD;                 // 128
    float* scA = Q1 + HD;
    float* shA = scA + HD;
    float* scB = shA + HD;
    float* shB = scB + HD;
    int* rowptr = (int*)(shB + HD);      // 50001 -> pad 50048
    int* cursor = rowptr + 50048;
    int* deg = cursor + 50048;
    int* blockSum = deg + 50048;         // 64
    int* blockOff = blockSum + 64;       // 64
    unsigned* csr = (unsigned*)(blockOff + 64);  // 800000

    hipMemsetAsync(deg, 0, NN * sizeof(int), stream);
    hipMemsetAsync(S1, 0, 2 * HD * sizeof(float), stream);

    const int SCAN_BLOCKS = (NN + 1023) / 1024;  // 49
    embed_kernel<<<(NN * 32) / 256, 256, 0, stream>>>(x_ids, node_emb, X);
    hist_kernel<<<(NE + 255) / 256, 256, 0, stream>>>(e_dst, deg);
    scan1_kernel<<<SCAN_BLOCKS, 1024, 0, stream>>>(deg, rowptr, blockSum);
    scan2_kernel<<<1, 64, 0, stream>>>(blockSum, blockOff, rowptr, SCAN_BLOCKS);
    scan3_kernel<<<SCAN_BLOCKS, 1024, 0, stream>>>(rowptr, cursor, blockOff);
    scatter_kernel<<<(NE + 255) / 256, 256, 0, stream>>>(e_src, e_dst, edge_attr, cursor, csr);

    const int mm_grid = (NN + 63) / 64;  // 782
    for (int i = 0; i <= NL; i++) {
        const float *W1, *b1, *g1, *be1, *W2, *b2, *g2, *be2;
        if (i == 0) {
            W1 = init_W1; b1 = init_b1; g1 = init_g1; be1 = init_be1;
            W2 = init_W2; b2 = init_b2; g2 = init_g2; be2 = init_be2;
        } else {
            W1 = mp_W1 + (size_t)(i - 1) * HD * HD; b1 = nullptr;
            g1 = mp_g1 + (size_t)(i - 1) * HD; be1 = mp_be1 + (size_t)(i - 1) * HD;
            W2 = mp_W2 + (size_t)(i - 1) * HD * HD; b2 = nullptr;
            g2 = mp_g2 + (size_t)(i - 1) * HD; be2 = mp_be2 + (size_t)(i - 1) * HD;
        }
        conv_kernel<<<(NN + 3) / 4, 256, 0, stream>>>(X, rowptr, csr, edge_emb, eps, i, scB,
                                                      shB, (i > 0) ? 1 : 0, Abuf);
        mm_kernel<<<mm_grid, 256, 0, stream>>>(Abuf, W1, b1, nullptr, nullptr, Bbuf, NN, S1, Q1);
        finalize_kernel<<<1, 128, 0, stream>>>(S1, Q1, g1, be1, 1.f / NN, scA, shA);
        mm_kernel<<<mm_grid, 256, 0, stream>>>(Bbuf, W2, b2, scA, shA, X, NN, S1, Q1);
        finalize_kernel<<<1, 128, 0, stream>>>(S1, Q1, g2, be2, 1.f / NN, scB, shB);
    }

    readout_kernel<<<NG, 128, 0, stream>>>(X, batch, scB, shB, Gp);

    // head: 4x (mm + finalize), count = 128
    mm_kernel<<<2, 256, 0, stream>>>(Gp, l1_W1, nullptr, nullptr, nullptr, Abuf, NG, S1, Q1);
    finalize_kernel<<<1, 128, 0, stream>>>(S1, Q1, l1_g1, l1_b1, 1.f / NG, scA, shA);
    mm_kernel<<<2, 256, 0, stream>>>(Abuf, l1_W2, nullptr, scA, shA, Bbuf, NG, S1, Q1);
    finalize_kernel<<<1, 128, 0, stream>>>(S1, Q1, l1_g2, l1_b2, 1.f / NG, scB, shB);
    mm_kernel<<<2, 256, 0, stream>>>(Bbuf, l2_W1, nullptr, scB, shB, Abuf, NG, S1, Q1);
    finalize_kernel<<<1, 128, 0, stream>>>(S1, Q1, l2_g1, l2_b1, 1.f / NG, scA, shA);
    mm_kernel<<<2, 256, 0, stream>>>(Abuf, l2_W2, nullptr, scA, shA, Bbuf, NG, S1, Q1);
    finalize_kernel<<<1, 128, 0, stream>>>(S1, Q1, l2_g2, l2_b2, 1.f / NG, scB, shB);

    final_kernel<<<1, 128, 0, stream>>>(Bbuf, scB, shB, fin_W, (float*)d_out);
}

// Round 3
// 1165.448 us; speedup vs baseline: 1.2501x; 1.1015x over previous
//
#include <hip/hip_runtime.h>

#define NN 50000
#define NE 800000
#define NG 128
#define HD 128
#define NL 4
#define BN_EPS 1e-5f

__device__ __forceinline__ float4 relu4(float4 v) {
    v.x = fmaxf(v.x, 0.f); v.y = fmaxf(v.y, 0.f);
    v.z = fmaxf(v.z, 0.f); v.w = fmaxf(v.w, 0.f);
    return v;
}

// ---------------- embed: x[n] = node_emb[x_ids[n]] ----------------
__global__ __launch_bounds__(256) void embed_kernel(const int* __restrict__ ids,
                                                    const float* __restrict__ emb,
                                                    float* __restrict__ x) {
    int i = blockIdx.x * 256 + threadIdx.x;      // over NN*32 float4 groups
    if (i < NN * 32) {
        int node = i >> 5, q = i & 31;
        int id = ids[node];
        float4 v = *(const float4*)(emb + (size_t)id * HD + 4 * q);
        *(float4*)(x + (size_t)node * HD + 4 * q) = v;
    }
}

// ---------------- CSR build ----------------
__global__ __launch_bounds__(256) void hist_kernel(const int* __restrict__ dst,
                                                   int* __restrict__ deg) {
    int e = blockIdx.x * 256 + threadIdx.x;
    if (e < NE) atomicAdd(&deg[dst[e]], 1);
}

// block-local inclusive scan -> rowptr holds local-exclusive, blockSum[b] = block total
__global__ __launch_bounds__(1024) void scan1_kernel(const int* __restrict__ deg,
                                                     int* __restrict__ rowptr,
                                                     int* __restrict__ blockSum) {
    __shared__ int s[1024];
    int b = blockIdx.x, t = threadIdx.x;
    int i = b * 1024 + t;
    int v = (i < NN) ? deg[i] : 0;
    s[t] = v;
    __syncthreads();
    for (int off = 1; off < 1024; off <<= 1) {
        int u = (t >= off) ? s[t - off] : 0;
        __syncthreads();
        s[t] += u;
        __syncthreads();
    }
    if (i < NN) rowptr[i] = s[t] - v;  // local exclusive
    if (t == 1023) blockSum[b] = s[1023];
}

// scan 49 block sums -> exclusive blockOff; write rowptr[NN]=total
__global__ __launch_bounds__(64) void scan2_kernel(const int* __restrict__ blockSum,
                                                   int* __restrict__ blockOff,
                                                   int* __restrict__ rowptr, int nblocks) {
    int t = threadIdx.x;
    int orig = (t < nblocks) ? blockSum[t] : 0;
    int v = orig;
    for (int off = 1; off < 64; off <<= 1) {
        int u = __shfl_up(v, off, 64);
        if (t >= off) v += u;
    }
    if (t < nblocks) blockOff[t] = v - orig;
    if (t == nblocks - 1) rowptr[NN] = v;
}

__global__ __launch_bounds__(1024) void scan3_kernel(int* __restrict__ rowptr,
                                                     int* __restrict__ cursor,
                                                     const int* __restrict__ blockOff) {
    int b = blockIdx.x, t = threadIdx.x;
    int i = b * 1024 + t;
    if (i < NN) {
        int r = rowptr[i] + blockOff[b];
        rowptr[i] = r;
        cursor[i] = r;
    }
}

__global__ __launch_bounds__(256) void scatter_kernel(const int* __restrict__ src,
                                                      const int* __restrict__ dst,
                                                      const int* __restrict__ attr,
                                                      int* __restrict__ cursor,
                                                      unsigned* __restrict__ csr) {
    int e = blockIdx.x * 256 + threadIdx.x;
    if (e < NE) {
        int d = dst[e];
        int pos = atomicAdd(&cursor[d], 1);
        csr[pos] = (unsigned)src[e] | ((unsigned)attr[e] << 16);  // src < 65536, attr < 8
    }
}

// ---------------- GINE conv ----------------
// wave64 per node; 32 lanes x float4 cover a 128-ch row, so each wave processes
// 2 edges per vector load (sub = lane>>5 picks the edge); unroll 2 -> 4 edges in flight.
__global__ __launch_bounds__(256) void conv_kernel(const float* __restrict__ x,
                                                   const int* __restrict__ rowptr,
                                                   const unsigned* __restrict__ csr,
                                                   const float* __restrict__ edge_emb,
                                                   const float* __restrict__ eps, int layer,
                                                   const float* __restrict__ sc,
                                                   const float* __restrict__ sh, int apply_act,
                                                   float* __restrict__ out) {
    __shared__ float elds[8 * HD];
    int t = threadIdx.x;
    ((float4*)elds)[t] = ((const float4*)edge_emb)[t];  // 8*128*4B = 4KB
    __syncthreads();
    int wave = t >> 6, lane = t & 63;
    int node = blockIdx.x * 4 + wave;
    if (node >= NN) return;
    int sub = lane >> 5;   // which edge of the pair
    int cq = lane & 31;    // float4 index within row
    int lo = rowptr[node], hi = rowptr[node + 1];
    float4 s4 = make_float4(1.f, 1.f, 1.f, 1.f);
    float4 h4 = make_float4(0.f, 0.f, 0.f, 0.f);
    if (apply_act) {
        s4 = *(const float4*)(sc + 4 * cq);
        h4 = *(const float4*)(sh + 4 * cq);
    }
    float4 acc = make_float4(0.f, 0.f, 0.f, 0.f);
    for (int base = lo; base < hi; base += 64) {
        unsigned pl = 0;
        int cnt = hi - base; if (cnt > 64) cnt = 64;
        if (base + lane < hi) pl = csr[base + lane];
        int j = 0;
        for (; j + 4 <= cnt; j += 4) {
            unsigned pa = __shfl(pl, j + sub, 64);
            unsigned pb = __shfl(pl, j + 2 + sub, 64);
            float4 xa = *(const float4*)(x + (size_t)(pa & 0xFFFFu) * HD + 4 * cq);
            float4 xb = *(const float4*)(x + (size_t)(pb & 0xFFFFu) * HD + 4 * cq);
            float4 ea = *(const float4*)&elds[(pa >> 16) * HD + 4 * cq];
            float4 eb = *(const float4*)&elds[(pb >> 16) * HD + 4 * cq];
            if (apply_act) {
                xa.x = fmaxf(fmaf(xa.x, s4.x, h4.x), 0.f);
                xa.y = fmaxf(fmaf(xa.y, s4.y, h4.y), 0.f);
                xa.z = fmaxf(fmaf(xa.z, s4.z, h4.z), 0.f);
                xa.w = fmaxf(fmaf(xa.w, s4.w, h4.w), 0.f);
                xb.x = fmaxf(fmaf(xb.x, s4.x, h4.x), 0.f);
                xb.y = fmaxf(fmaf(xb.y, s4.y, h4.y), 0.f);
                xb.z = fmaxf(fmaf(xb.z, s4.z, h4.z), 0.f);
                xb.w = fmaxf(fmaf(xb.w, s4.w, h4.w), 0.f);
            }
            acc.x += fmaxf(xa.x + ea.x, 0.f) + fmaxf(xb.x + eb.x, 0.f);
            acc.y += fmaxf(xa.y + ea.y, 0.f) + fmaxf(xb.y + eb.y, 0.f);
            acc.z += fmaxf(xa.z + ea.z, 0.f) + fmaxf(xb.z + eb.z, 0.f);
            acc.w += fmaxf(xa.w + ea.w, 0.f) + fmaxf(xb.w + eb.w, 0.f);
        }
        for (; j < cnt; j += 2) {
            int je = j + sub;
            int valid = (je < cnt);
            unsigned p = __shfl(pl, valid ? je : j, 64);
            float4 xa = *(const float4*)(x + (size_t)(p & 0xFFFFu) * HD + 4 * cq);
            float4 ea = *(const float4*)&elds[(p >> 16) * HD + 4 * cq];
            if (apply_act) {
                xa.x = fmaxf(fmaf(xa.x, s4.x, h4.x), 0.f);
                xa.y = fmaxf(fmaf(xa.y, s4.y, h4.y), 0.f);
                xa.z = fmaxf(fmaf(xa.z, s4.z, h4.z), 0.f);
                xa.w = fmaxf(fmaf(xa.w, s4.w, h4.w), 0.f);
            }
            float m = valid ? 1.f : 0.f;
            acc.x += m * fmaxf(xa.x + ea.x, 0.f);
            acc.y += m * fmaxf(xa.y + ea.y, 0.f);
            acc.z += m * fmaxf(xa.z + ea.z, 0.f);
            acc.w += m * fmaxf(xa.w + ea.w, 0.f);
        }
    }
    // combine the two edge-halves: lane l and l^32 hold same channels
    acc.x += __shfl_xor(acc.x, 32, 64);
    acc.y += __shfl_xor(acc.y, 32, 64);
    acc.z += __shfl_xor(acc.z, 32, 64);
    acc.w += __shfl_xor(acc.w, 32, 64);
    if (sub == 0) {
        float ep = eps[layer];
        float4 xs = *(const float4*)(x + (size_t)node * HD + 4 * cq);
        if (apply_act) {
            xs.x = fmaxf(fmaf(xs.x, s4.x, h4.x), 0.f);
            xs.y = fmaxf(fmaf(xs.y, s4.y, h4.y), 0.f);
            xs.z = fmaxf(fmaf(xs.z, s4.z, h4.z), 0.f);
            xs.w = fmaxf(fmaf(xs.w, s4.w, h4.w), 0.f);
        }
        float4 o;
        o.x = (1.f + ep) * xs.x + acc.x;
        o.y = (1.f + ep) * xs.y + acc.y;
        o.z = (1.f + ep) * xs.z + acc.z;
        o.w = (1.f + ep) * xs.w + acc.w;
        *(float4*)(out + (size_t)node * HD + 4 * cq) = o;
    }
}

// ---------------- matmul: out = act_in(A) @ W (+bias); accumulate col sum/sumsq ----------------
__global__ __launch_bounds__(256) void mm_kernel(const float* __restrict__ A,
                                                 const float* __restrict__ W,
                                                 const float* __restrict__ bias,
                                                 const float* __restrict__ sc_in,
                                                 const float* __restrict__ sh_in,
                                                 float* __restrict__ out, int nrows,
                                                 float* __restrict__ stats_s,
                                                 float* __restrict__ stats_q) {
    const int PADK = 132;  // stride in dwords: %32==4 -> distinct banks across i; 16B-aligned rows
    __shared__ float As[64 * PADK];
    __shared__ float colS[HD], colQ[HD];
    int t = threadIdx.x;
    if (t < HD) { colS[t] = 0.f; colQ[t] = 0.f; }
    int row0 = blockIdx.x * 64;
#pragma unroll
    for (int i = 0; i < 8; i++) {
        int idx = t + i * 256;  // 0..2047
        int r = idx >> 5, kq = idx & 31;
        float4 v = make_float4(0.f, 0.f, 0.f, 0.f);
        int gr = row0 + r;
        if (gr < nrows) v = *(const float4*)(A + (size_t)gr * HD + 4 * kq);
        if (sc_in) {
            float4 s4 = *(const float4*)(sc_in + 4 * kq);
            float4 h4 = *(const float4*)(sh_in + 4 * kq);
            v.x = fmaxf(fmaf(v.x, s4.x, h4.x), 0.f);
            v.y = fmaxf(fmaf(v.y, s4.y, h4.y), 0.f);
            v.z = fmaxf(fmaf(v.z, s4.z, h4.z), 0.f);
            v.w = fmaxf(fmaf(v.w, s4.w, h4.w), 0.f);
        }
        *(float4*)&As[r * PADK + 4 * kq] = v;
    }
    __syncthreads();
    int jq = t & 31, rb = t >> 5;
    float acc[8][4];
#pragma unroll
    for (int i = 0; i < 8; i++)
#pragma unroll
        for (int j = 0; j < 4; j++) acc[i][j] = 0.f;
    const float* Wp = W + 4 * jq;
    const float* Ap = &As[rb * 8 * PADK];
    for (int k = 0; k < HD; k += 4) {
        float4 w0 = *(const float4*)(Wp + (size_t)(k + 0) * HD);
        float4 w1 = *(const float4*)(Wp + (size_t)(k + 1) * HD);
        float4 w2 = *(const float4*)(Wp + (size_t)(k + 2) * HD);
        float4 w3 = *(const float4*)(Wp + (size_t)(k + 3) * HD);
#pragma unroll
        for (int i = 0; i < 8; i++) {
            float4 a4 = *(const float4*)&Ap[i * PADK + k];
            acc[i][0] = fmaf(a4.x, w0.x, acc[i][0]);
            acc[i][1] = fmaf(a4.x, w0.y, acc[i][1]);
            acc[i][2] = fmaf(a4.x, w0.z, acc[i][2]);
            acc[i][3] = fmaf(a4.x, w0.w, acc[i][3]);
            acc[i][0] = fmaf(a4.y, w1.x, acc[i][0]);
            acc[i][1] = fmaf(a4.y, w1.y, acc[i][1]);
            acc[i][2] = fmaf(a4.y, w1.z, acc[i][2]);
            acc[i][3] = fmaf(a4.y, w1.w, acc[i][3]);
            acc[i][0] = fmaf(a4.z, w2.x, acc[i][0]);
            acc[i][1] = fmaf(a4.z, w2.y, acc[i][1]);
            acc[i][2] = fmaf(a4.z, w2.z, acc[i][2]);
            acc[i][3] = fmaf(a4.z, w2.w, acc[i][3]);
            acc[i][0] = fmaf(a4.w, w3.x, acc[i][0]);
            acc[i][1] = fmaf(a4.w, w3.y, acc[i][1]);
            acc[i][2] = fmaf(a4.w, w3.z, acc[i][2]);
            acc[i][3] = fmaf(a4.w, w3.w, acc[i][3]);
        }
    }
    float4 b4 = make_float4(0.f, 0.f, 0.f, 0.f);
    if (bias) b4 = *(const float4*)(bias + 4 * jq);
    float s0 = 0, s1 = 0, s2 = 0, s3 = 0, q0 = 0, q1 = 0, q2 = 0, q3 = 0;
#pragma unroll
    for (int i = 0; i < 8; i++) {
        int gr = row0 + rb * 8 + i;
        if (gr < nrows) {
            float4 v;
            v.x = acc[i][0] + b4.x;
            v.y = acc[i][1] + b4.y;
            v.z = acc[i][2] + b4.z;
            v.w = acc[i][3] + b4.w;
            *(float4*)(out + (size_t)gr * HD + 4 * jq) = v;
            s0 += v.x; q0 += v.x * v.x;
            s1 += v.y; q1 += v.y * v.y;
            s2 += v.z; q2 += v.z * v.z;
            s3 += v.w; q3 += v.w * v.w;
        }
    }
    atomicAdd(&colS[4 * jq + 0], s0); atomicAdd(&colQ[4 * jq + 0], q0);
    atomicAdd(&colS[4 * jq + 1], s1); atomicAdd(&colQ[4 * jq + 1], q1);
    atomicAdd(&colS[4 * jq + 2], s2); atomicAdd(&colQ[4 * jq + 2], q2);
    atomicAdd(&colS[4 * jq + 3], s3); atomicAdd(&colQ[4 * jq + 3], q3);
    __syncthreads();
    if (t < HD) {
        atomicAdd(&stats_s[t], colS[t]);
        atomicAdd(&stats_q[t], colQ[t]);
    }
}

// ---------------- BN stats -> (scale, shift); zero stats for next use ----------------
__global__ __launch_bounds__(128) void finalize_kernel(float* __restrict__ ss, float* __restrict__ sq,
                                                       const float* __restrict__ gam,
                                                       const float* __restrict__ bet, float inv_cnt,
                                                       float* __restrict__ sc, float* __restrict__ sh) {
    int t = threadIdx.x;  // 128
    float s = ss[t], q = sq[t];
    float m = s * inv_cnt;
    float v = fmaf(q, inv_cnt, -m * m);
    v = fmaxf(v, 0.f);
    float inv = rsqrtf(v + BN_EPS);
    float scale = gam[t] * inv;
    sc[t] = scale;
    sh[t] = fmaf(-m, scale, bet[t]);
    ss[t] = 0.f;
    sq[t] = 0.f;
}

// ---------------- readout: g[b] += sum over its nodes of act(x) ----------------
// 256 threads: rq = t>>5 row-lane (8 rows in parallel), cq = t&31 float4 channel group.
// Per-thread register accumulator keyed on (sorted) batch id; atomic flush on change.
__global__ __launch_bounds__(256) void readout_kernel(const float* __restrict__ x,
                                                      const int* __restrict__ batch,
                                                      const float* __restrict__ sc,
                                                      const float* __restrict__ sh,
                                                      float* __restrict__ gout) {
    __shared__ int bat[256];
    int t = threadIdx.x;
    int rq = t >> 5, cq = t & 31;
    int r0 = blockIdx.x * 256;
    int i = r0 + t;
    bat[t] = (i < NN) ? batch[i] : -1;
    __syncthreads();
    float4 s4 = *(const float4*)(sc + 4 * cq);
    float4 h4 = *(const float4*)(sh + 4 * cq);
    float4 acc = make_float4(0.f, 0.f, 0.f, 0.f);
    int gcur = -1;
    for (int j = rq; j < 256; j += 8) {
        int r = r0 + j;
        if (r >= NN) break;
        int g = bat[j];
        if (g != gcur) {
            if (gcur >= 0) {
                atomicAdd(&gout[(size_t)gcur * HD + 4 * cq + 0], acc.x);
                atomicAdd(&gout[(size_t)gcur * HD + 4 * cq + 1], acc.y);
                atomicAdd(&gout[(size_t)gcur * HD + 4 * cq + 2], acc.z);
                atomicAdd(&gout[(size_t)gcur * HD + 4 * cq + 3], acc.w);
            }
            acc = make_float4(0.f, 0.f, 0.f, 0.f);
            gcur = g;
        }
        float4 v = *(const float4*)(x + (size_t)r * HD + 4 * cq);
        acc.x += fmaxf(fmaf(v.x, s4.x, h4.x), 0.f);
        acc.y += fmaxf(fmaf(v.y, s4.y, h4.y), 0.f);
        acc.z += fmaxf(fmaf(v.z, s4.z, h4.z), 0.f);
        acc.w += fmaxf(fmaf(v.w, s4.w, h4.w), 0.f);
    }
    if (gcur >= 0) {
        atomicAdd(&gout[(size_t)gcur * HD + 4 * cq + 0], acc.x);
        atomicAdd(&gout[(size_t)gcur * HD + 4 * cq + 1], acc.y);
        atomicAdd(&gout[(size_t)gcur * HD + 4 * cq + 2], acc.z);
        atomicAdd(&gout[(size_t)gcur * HD + 4 * cq + 3], acc.w);
    }
}

// ---------------- final: out[g] = act(h[g]) . fin_W ----------------
__global__ __launch_bounds__(128) void final_kernel(const float* __restrict__ h,
                                                    const float* __restrict__ sc,
                                                    const float* __restrict__ sh,
                                                    const float* __restrict__ finW,
                                                    float* __restrict__ out) {
    int t = threadIdx.x;  // 128 = graph
    float s = 0.f;
    for (int c = 0; c < HD; c++) {
        float v = h[(size_t)t * HD + c];
        v = fmaxf(fmaf(v, sc[c], sh[c]), 0.f);
        s += v * finW[c];
    }
    out[t] = s;
}

extern "C" void kernel_launch(void* const* d_in, const int* in_sizes, int n_in,
                              void* d_out, int out_size, void* d_ws, size_t ws_size,
                              hipStream_t stream) {
    const int* x_ids = (const int*)d_in[0];
    const int* edge_index = (const int*)d_in[1];
    const int* batch = (const int*)d_in[2];
    const int* edge_attr = (const int*)d_in[3];
    const float* node_emb = (const float*)d_in[4];
    const float* edge_emb = (const float*)d_in[5];
    const float* eps = (const float*)d_in[6];
    const float* init_W1 = (const float*)d_in[7];
    const float* init_b1 = (const float*)d_in[8];
    const float* init_g1 = (const float*)d_in[9];
    const float* init_be1 = (const float*)d_in[10];
    const float* init_W2 = (const float*)d_in[11];
    const float* init_b2 = (const float*)d_in[12];
    const float* init_g2 = (const float*)d_in[13];
    const float* init_be2 = (const float*)d_in[14];
    const float* mp_W1 = (const float*)d_in[15];
    const float* mp_g1 = (const float*)d_in[16];
    const float* mp_be1 = (const float*)d_in[17];
    const float* mp_W2 = (const float*)d_in[18];
    const float* mp_g2 = (const float*)d_in[19];
    const float* mp_be2 = (const float*)d_in[20];
    const float* l1_W1 = (const float*)d_in[21];
    const float* l1_g1 = (const float*)d_in[22];
    const float* l1_b1 = (const float*)d_in[23];
    const float* l1_W2 = (const float*)d_in[24];
    const float* l1_g2 = (const float*)d_in[25];
    const float* l1_b2 = (const float*)d_in[26];
    const float* l2_W1 = (const float*)d_in[27];
    const float* l2_g1 = (const float*)d_in[28];
    const float* l2_b1 = (const float*)d_in[29];
    const float* l2_W2 = (const float*)d_in[30];
    const float* l2_g2 = (const float*)d_in[31];
    const float* l2_b2 = (const float*)d_in[32];
    const float* fin_W = (const float*)d_in[33];

    const int* e_src = edge_index;
    const int* e_dst = edge_index + NE;

    // workspace layout (floats)
    float* ws = (float*)d_ws;
    float* X = ws;                       // 50000*128
    float* Abuf = X + (size_t)NN * HD;   // 50000*128
    float* Bbuf = Abuf + (size_t)NN * HD;
    float* Gp = Bbuf + (size_t)NN * HD;  // 128*128
    float* S1 = Gp + NG * HD;            // 128
    float* Q1 = S1 + HD;                 // 128
    float* scA = Q1 + HD;
    float* shA = scA + HD;
    float* scB = shA + HD;
    float* shB = scB + HD;
    int* rowptr = (int*)(shB + HD);      // 50001 -> pad 50048
    int* cursor = rowptr + 50048;
    int* deg = cursor + 50048;
    int* blockSum = deg + 50048;         // 64
    int* blockOff = blockSum + 64;       // 64
    unsigned* csr = (unsigned*)(blockOff + 64);  // 800000

    hipMemsetAsync(deg, 0, NN * sizeof(int), stream);
    hipMemsetAsync(S1, 0, 2 * HD * sizeof(float), stream);
    hipMemsetAsync(Gp, 0, NG * HD * sizeof(float), stream);

    const int SCAN_BLOCKS = (NN + 1023) / 1024;  // 49
    embed_kernel<<<(NN * 32) / 256, 256, 0, stream>>>(x_ids, node_emb, X);
    hist_kernel<<<(NE + 255) / 256, 256, 0, stream>>>(e_dst, deg);
    scan1_kernel<<<SCAN_BLOCKS, 1024, 0, stream>>>(deg, rowptr, blockSum);
    scan2_kernel<<<1, 64, 0, stream>>>(blockSum, blockOff, rowptr, SCAN_BLOCKS);
    scan3_kernel<<<SCAN_BLOCKS, 1024, 0, stream>>>(rowptr, cursor, blockOff);
    scatter_kernel<<<(NE + 255) / 256, 256, 0, stream>>>(e_src, e_dst, edge_attr, cursor, csr);

    const int mm_grid = (NN + 63) / 64;  // 782
    for (int i = 0; i <= NL; i++) {
        const float *W1, *b1, *g1, *be1, *W2, *b2, *g2, *be2;
        if (i == 0) {
            W1 = init_W1; b1 = init_b1; g1 = init_g1; be1 = init_be1;
            W2 = init_W2; b2 = init_b2; g2 = init_g2; be2 = init_be2;
        } else {
            W1 = mp_W1 + (size_t)(i - 1) * HD * HD; b1 = nullptr;
            g1 = mp_g1 + (size_t)(i - 1) * HD; be1 = mp_be1 + (size_t)(i - 1) * HD;
            W2 = mp_W2 + (size_t)(i - 1) * HD * HD; b2 = nullptr;
            g2 = mp_g2 + (size_t)(i - 1) * HD; be2 = mp_be2 + (size_t)(i - 1) * HD;
        }
        conv_kernel<<<(NN + 3) / 4, 256, 0, stream>>>(X, rowptr, csr, edge_emb, eps, i, scB,
                                                      shB, (i > 0) ? 1 : 0, Abuf);
        mm_kernel<<<mm_grid, 256, 0, stream>>>(Abuf, W1, b1, nullptr, nullptr, Bbuf, NN, S1, Q1);
        finalize_kernel<<<1, 128, 0, stream>>>(S1, Q1, g1, be1, 1.f / NN, scA, shA);
        mm_kernel<<<mm_grid, 256, 0, stream>>>(Bbuf, W2, b2, scA, shA, X, NN, S1, Q1);
        finalize_kernel<<<1, 128, 0, stream>>>(S1, Q1, g2, be2, 1.f / NN, scB, shB);
    }

    readout_kernel<<<(NN + 255) / 256, 256, 0, stream>>>(X, batch, scB, shB, Gp);

    // head: 4x (mm + finalize), count = 128
    mm_kernel<<<2, 256, 0, stream>>>(Gp, l1_W1, nullptr, nullptr, nullptr, Abuf, NG, S1, Q1);
    finalize_kernel<<<1, 128, 0, stream>>>(S1, Q1, l1_g1, l1_b1, 1.f / NG, scA, shA);
    mm_kernel<<<2, 256, 0, stream>>>(Abuf, l1_W2, nullptr, scA, shA, Bbuf, NG, S1, Q1);
    finalize_kernel<<<1, 128, 0, stream>>>(S1, Q1, l1_g2, l1_b2, 1.f / NG, scB, shB);
    mm_kernel<<<2, 256, 0, stream>>>(Bbuf, l2_W1, nullptr, scB, shB, Abuf, NG, S1, Q1);
    finalize_kernel<<<1, 128, 0, stream>>>(S1, Q1, l2_g1, l2_b1, 1.f / NG, scA, shA);
    mm_kernel<<<2, 256, 0, stream>>>(Abuf, l2_W2, nullptr, scA, shA, Bbuf, NG, S1, Q1);
    finalize_kernel<<<1, 128, 0, stream>>>(S1, Q1, l2_g2, l2_b2, 1.f / NG, scB, shB);

    final_kernel<<<1, 128, 0, stream>>>(Bbuf, scB, shB, fin_W, (float*)d_out);
}

// Round 5
// 1016.291 us; speedup vs baseline: 1.4335x; 1.1468x over previous
//
#include <hip/hip_runtime.h>

#define NN 50000
#define NE 800000
#define NG 128
#define HD 128
#define NL 4
#define BN_EPS 1e-5f

typedef __attribute__((ext_vector_type(8))) short bf16x8;
typedef __attribute__((ext_vector_type(4))) float f32x4;

__device__ __forceinline__ float bfval(unsigned short h) { return __uint_as_float((unsigned)h << 16); }
__device__ __forceinline__ unsigned short f2bf(float f) {
    unsigned u = __float_as_uint(f);
    u += 0x7FFFu + ((u >> 16) & 1u);  // RNE
    return (unsigned short)(u >> 16);
}

// ---------------- embed: x[n] = node_emb[x_ids[n]] (fp32) ----------------
__global__ __launch_bounds__(256) void embed_kernel(const int* __restrict__ ids,
                                                    const float* __restrict__ emb,
                                                    float* __restrict__ x) {
    int i = blockIdx.x * 256 + threadIdx.x;
    if (i < NN * 32) {
        int node = i >> 5, q = i & 31;
        int id = ids[node];
        float4 v = *(const float4*)(emb + (size_t)id * HD + 4 * q);
        *(float4*)(x + (size_t)node * HD + 4 * q) = v;
    }
}

// ---------------- weight convert: split W[k][n] fp32 -> Wh/Wl bf16 [n][k] ----------------
// layout: [iW1][iW2][mpW1 x4][mpW2 x4], 16384 elems each
__global__ __launch_bounds__(256) void cvtw_kernel(const float* __restrict__ iw1,
                                                   const float* __restrict__ iw2,
                                                   const float* __restrict__ mw1,
                                                   const float* __restrict__ mw2,
                                                   unsigned short* __restrict__ Wh,
                                                   unsigned short* __restrict__ Wl) {
    int i = blockIdx.x * 256 + threadIdx.x;  // 163840 total
    if (i >= 163840) return;
    float v;
    int base, loc;
    if (i < 16384)      { v = iw1[i];          base = 0;              loc = i; }
    else if (i < 32768) { v = iw2[i - 16384];  base = 16384;          loc = i - 16384; }
    else if (i < 98304) { int j = i - 32768; v = mw1[j]; base = 32768 + (j >> 14) * 16384; loc = j & 16383; }
    else                { int j = i - 98304; v = mw2[j]; base = 98304 + (j >> 14) * 16384; loc = j & 16383; }
    int k = loc >> 7, n = loc & 127;
    unsigned short h = f2bf(v);
    float r = v - bfval(h);
    Wh[base + n * 128 + k] = h;
    Wl[base + n * 128 + k] = f2bf(r);
}

// ---------------- CSR build ----------------
__global__ __launch_bounds__(256) void hist_kernel(const int* __restrict__ dst,
                                                   int* __restrict__ deg) {
    int e = blockIdx.x * 256 + threadIdx.x;
    if (e < NE) atomicAdd(&deg[dst[e]], 1);
}

__global__ __launch_bounds__(1024) void scan1_kernel(const int* __restrict__ deg,
                                                     int* __restrict__ rowptr,
                                                     int* __restrict__ blockSum) {
    __shared__ int s[1024];
    int b = blockIdx.x, t = threadIdx.x;
    int i = b * 1024 + t;
    int v = (i < NN) ? deg[i] : 0;
    s[t] = v;
    __syncthreads();
    for (int off = 1; off < 1024; off <<= 1) {
        int u = (t >= off) ? s[t - off] : 0;
        __syncthreads();
        s[t] += u;
        __syncthreads();
    }
    if (i < NN) rowptr[i] = s[t] - v;
    if (t == 1023) blockSum[b] = s[1023];
}

__global__ __launch_bounds__(64) void scan2_kernel(const int* __restrict__ blockSum,
                                                   int* __restrict__ blockOff,
                                                   int* __restrict__ rowptr, int nblocks) {
    int t = threadIdx.x;
    int orig = (t < nblocks) ? blockSum[t] : 0;
    int v = orig;
    for (int off = 1; off < 64; off <<= 1) {
        int u = __shfl_up(v, off, 64);
        if (t >= off) v += u;
    }
    if (t < nblocks) blockOff[t] = v - orig;
    if (t == nblocks - 1) rowptr[NN] = v;
}

__global__ __launch_bounds__(1024) void scan3_kernel(int* __restrict__ rowptr,
                                                     int* __restrict__ cursor,
                                                     const int* __restrict__ blockOff) {
    int b = blockIdx.x, t = threadIdx.x;
    int i = b * 1024 + t;
    if (i < NN) {
        int r = rowptr[i] + blockOff[b];
        rowptr[i] = r;
        cursor[i] = r;
    }
}

__global__ __launch_bounds__(256) void scatter_kernel(const int* __restrict__ src,
                                                      const int* __restrict__ dst,
                                                      const int* __restrict__ attr,
                                                      int* __restrict__ cursor,
                                                      unsigned* __restrict__ csr) {
    int e = blockIdx.x * 256 + threadIdx.x;
    if (e < NE) {
        int d = dst[e];
        int pos = atomicAdd(&cursor[d], 1);
        csr[pos] = (unsigned)src[e] | ((unsigned)attr[e] << 16);
    }
}

// ---------------- GINE conv (fp32, round-3 proven version) ----------------
__global__ __launch_bounds__(256) void conv_kernel(const float* __restrict__ x,
                                                   const int* __restrict__ rowptr,
                                                   const unsigned* __restrict__ csr,
                                                   const float* __restrict__ edge_emb,
                                                   const float* __restrict__ eps, int layer,
                                                   const float* __restrict__ sc,
                                                   const float* __restrict__ sh, int apply_act,
                                                   float* __restrict__ out) {
    __shared__ float elds[8 * HD];
    int t = threadIdx.x;
    ((float4*)elds)[t] = ((const float4*)edge_emb)[t];
    __syncthreads();
    int wave = t >> 6, lane = t & 63;
    int node = blockIdx.x * 4 + wave;
    if (node >= NN) return;
    int sub = lane >> 5;
    int cq = lane & 31;
    int lo = rowptr[node], hi = rowptr[node + 1];
    float4 s4 = make_float4(1.f, 1.f, 1.f, 1.f);
    float4 h4 = make_float4(0.f, 0.f, 0.f, 0.f);
    if (apply_act) {
        s4 = *(const float4*)(sc + 4 * cq);
        h4 = *(const float4*)(sh + 4 * cq);
    }
    float4 acc = make_float4(0.f, 0.f, 0.f, 0.f);
    for (int base = lo; base < hi; base += 64) {
        unsigned pl = 0;
        int cnt = hi - base; if (cnt > 64) cnt = 64;
        if (base + lane < hi) pl = csr[base + lane];
        int j = 0;
        for (; j + 4 <= cnt; j += 4) {
            unsigned pa = __shfl(pl, j + sub, 64);
            unsigned pb = __shfl(pl, j + 2 + sub, 64);
            float4 xa = *(const float4*)(x + (size_t)(pa & 0xFFFFu) * HD + 4 * cq);
            float4 xb = *(const float4*)(x + (size_t)(pb & 0xFFFFu) * HD + 4 * cq);
            float4 ea = *(const float4*)&elds[(pa >> 16) * HD + 4 * cq];
            float4 eb = *(const float4*)&elds[(pb >> 16) * HD + 4 * cq];
            if (apply_act) {
                xa.x = fmaxf(fmaf(xa.x, s4.x, h4.x), 0.f);
                xa.y = fmaxf(fmaf(xa.y, s4.y, h4.y), 0.f);
                xa.z = fmaxf(fmaf(xa.z, s4.z, h4.z), 0.f);
                xa.w = fmaxf(fmaf(xa.w, s4.w, h4.w), 0.f);
                xb.x = fmaxf(fmaf(xb.x, s4.x, h4.x), 0.f);
                xb.y = fmaxf(fmaf(xb.y, s4.y, h4.y), 0.f);
                xb.z = fmaxf(fmaf(xb.z, s4.z, h4.z), 0.f);
                xb.w = fmaxf(fmaf(xb.w, s4.w, h4.w), 0.f);
            }
            acc.x += fmaxf(xa.x + ea.x, 0.f) + fmaxf(xb.x + eb.x, 0.f);
            acc.y += fmaxf(xa.y + ea.y, 0.f) + fmaxf(xb.y + eb.y, 0.f);
            acc.z += fmaxf(xa.z + ea.z, 0.f) + fmaxf(xb.z + eb.z, 0.f);
            acc.w += fmaxf(xa.w + ea.w, 0.f) + fmaxf(xb.w + eb.w, 0.f);
        }
        for (; j < cnt; j += 2) {
            int je = j + sub;
            int valid = (je < cnt);
            unsigned p = __shfl(pl, valid ? je : j, 64);
            float4 xa = *(const float4*)(x + (size_t)(p & 0xFFFFu) * HD + 4 * cq);
            float4 ea = *(const float4*)&elds[(p >> 16) * HD + 4 * cq];
            if (apply_act) {
                xa.x = fmaxf(fmaf(xa.x, s4.x, h4.x), 0.f);
                xa.y = fmaxf(fmaf(xa.y, s4.y, h4.y), 0.f);
                xa.z = fmaxf(fmaf(xa.z, s4.z, h4.z), 0.f);
                xa.w = fmaxf(fmaf(xa.w, s4.w, h4.w), 0.f);
            }
            float m = valid ? 1.f : 0.f;
            acc.x += m * fmaxf(xa.x + ea.x, 0.f);
            acc.y += m * fmaxf(xa.y + ea.y, 0.f);
            acc.z += m * fmaxf(xa.z + ea.z, 0.f);
            acc.w += m * fmaxf(xa.w + ea.w, 0.f);
        }
    }
    acc.x += __shfl_xor(acc.x, 32, 64);
    acc.y += __shfl_xor(acc.y, 32, 64);
    acc.z += __shfl_xor(acc.z, 32, 64);
    acc.w += __shfl_xor(acc.w, 32, 64);
    if (sub == 0) {
        float ep = eps[layer];
        float4 xs = *(const float4*)(x + (size_t)node * HD + 4 * cq);
        if (apply_act) {
            xs.x = fmaxf(fmaf(xs.x, s4.x, h4.x), 0.f);
            xs.y = fmaxf(fmaf(xs.y, s4.y, h4.y), 0.f);
            xs.z = fmaxf(fmaf(xs.z, s4.z, h4.z), 0.f);
            xs.w = fmaxf(fmaf(xs.w, s4.w, h4.w), 0.f);
        }
        float4 o;
        o.x = (1.f + ep) * xs.x + acc.x;
        o.y = (1.f + ep) * xs.y + acc.y;
        o.z = (1.f + ep) * xs.z + acc.z;
        o.w = (1.f + ep) * xs.w + acc.w;
        *(float4*)(out + (size_t)node * HD + 4 * cq) = o;
    }
}

// ---------------- split-precision MFMA matmul: out(fp32) = act(A fp32) @ W (+bias) ----------------
// A split to bf16 hi+lo in registers; W pre-split to Wh/Wl bf16 [n][k].
// D = Ah@Wh + Al@Wh + Ah@Wl  (error ~2^-17, numerically ~fp32)
__device__ __forceinline__ void loadA_split(const float* __restrict__ A, int row, int k0,
                                            bool ok, const float* __restrict__ sc,
                                            const float* __restrict__ sh,
                                            bf16x8& hi, bf16x8& lo) {
    union { unsigned u[4]; bf16x8 v; } H, L;
    if (!ok) { hi = (bf16x8)0; lo = (bf16x8)0; return; }
    const float* p = A + (size_t)row * HD + k0;
    float4 v0 = *(const float4*)p;
    float4 v1 = *(const float4*)(p + 4);
    float f[8] = {v0.x, v0.y, v0.z, v0.w, v1.x, v1.y, v1.z, v1.w};
    if (sc) {
        float4 s0 = *(const float4*)(sc + k0), s1 = *(const float4*)(sc + k0 + 4);
        float4 h0 = *(const float4*)(sh + k0), h1 = *(const float4*)(sh + k0 + 4);
        float ss[8] = {s0.x, s0.y, s0.z, s0.w, s1.x, s1.y, s1.z, s1.w};
        float hh[8] = {h0.x, h0.y, h0.z, h0.w, h1.x, h1.y, h1.z, h1.w};
#pragma unroll
        for (int i = 0; i < 8; i++) f[i] = fmaxf(fmaf(f[i], ss[i], hh[i]), 0.f);
    }
#pragma unroll
    for (int i = 0; i < 4; i++) {
        unsigned short ha = f2bf(f[2 * i]);
        unsigned short hb = f2bf(f[2 * i + 1]);
        unsigned short la = f2bf(f[2 * i] - bfval(ha));
        unsigned short lb = f2bf(f[2 * i + 1] - bfval(hb));
        H.u[i] = (unsigned)ha | ((unsigned)hb << 16);
        L.u[i] = (unsigned)la | ((unsigned)lb << 16);
    }
    hi = H.v;
    lo = L.v;
}

// Block 256 = 4 waves covering 128 rows; wave -> 32 rows (2 tiles of 16) x 128 cols (8 tiles).
__global__ __launch_bounds__(256) void mm_mfma(const float* __restrict__ A,
                                               const unsigned short* __restrict__ Wh,
                                               const unsigned short* __restrict__ Wl,
                                               const float* __restrict__ bias,
                                               const float* __restrict__ sc_in,
                                               const float* __restrict__ sh_in,
                                               float* __restrict__ out,
                                               float* __restrict__ stats_s,
                                               float* __restrict__ stats_q) {
    __shared__ float colS[HD], colQ[HD];
    int t = threadIdx.x;
    if (t < HD) { colS[t] = 0.f; colQ[t] = 0.f; }
    __syncthreads();
    int w = t >> 6, lane = t & 63;
    int quad = lane >> 4, nl = lane & 15;
    int row0 = blockIdx.x * 128 + w * 32;
    int rA0 = row0 + nl, rA1 = row0 + 16 + nl;
    bool ok0 = rA0 < NN, ok1 = rA1 < NN;
    f32x4 acc[16];
#pragma unroll
    for (int i = 0; i < 16; i++) acc[i] = (f32x4){0.f, 0.f, 0.f, 0.f};
#pragma unroll
    for (int kc = 0; kc < 4; kc++) {
        int k0 = kc * 32 + quad * 8;
        bf16x8 a0h, a0l, a1h, a1l;
        loadA_split(A, rA0, k0, ok0, sc_in, sh_in, a0h, a0l);
        loadA_split(A, rA1, k0, ok1, sc_in, sh_in, a1h, a1l);
#pragma unroll
        for (int c = 0; c < 8; c++) {
            size_t widx = (size_t)(c * 16 + nl) * HD + k0;
            bf16x8 bh = *(const bf16x8*)(Wh + widx);
            bf16x8 bl = *(const bf16x8*)(Wl + widx);
            acc[c] = __builtin_amdgcn_mfma_f32_16x16x32_bf16(a0h, bh, acc[c], 0, 0, 0);
            acc[c] = __builtin_amdgcn_mfma_f32_16x16x32_bf16(a0l, bh, acc[c], 0, 0, 0);
            acc[c] = __builtin_amdgcn_mfma_f32_16x16x32_bf16(a0h, bl, acc[c], 0, 0, 0);
            acc[8 + c] = __builtin_amdgcn_mfma_f32_16x16x32_bf16(a1h, bh, acc[8 + c], 0, 0, 0);
            acc[8 + c] = __builtin_amdgcn_mfma_f32_16x16x32_bf16(a1l, bh, acc[8 + c], 0, 0, 0);
            acc[8 + c] = __builtin_amdgcn_mfma_f32_16x16x32_bf16(a1h, bl, acc[8 + c], 0, 0, 0);
        }
    }
#pragma unroll
    for (int h = 0; h < 2; h++) {
        int baserow = row0 + h * 16 + quad * 4;
#pragma unroll
        for (int c = 0; c < 8; c++) {
            int col = c * 16 + nl;
            float bv = bias ? bias[col] : 0.f;
            f32x4 v = acc[h * 8 + c];
            float s = 0.f, qq = 0.f;
#pragma unroll
            for (int r = 0; r < 4; r++) {
                int gr = baserow + r;
                float val = v[r] + bv;
                if (gr < NN) {
                    out[(size_t)gr * HD + col] = val;
                    s += val;
                    qq += val * val;
                }
            }
            s += __shfl_xor(s, 16, 64);  s += __shfl_xor(s, 32, 64);
            qq += __shfl_xor(qq, 16, 64); qq += __shfl_xor(qq, 32, 64);
            if (quad == 0) {
                atomicAdd(&colS[col], s);
                atomicAdd(&colQ[col], qq);
            }
        }
    }
    __syncthreads();
    if (t < HD) {
        atomicAdd(&stats_s[t], colS[t]);
        atomicAdd(&stats_q[t], colQ[t]);
    }
}

// ---------------- BN stats -> (scale, shift); zero stats for next use ----------------
__global__ __launch_bounds__(128) void finalize_kernel(float* __restrict__ ss, float* __restrict__ sq,
                                                       const float* __restrict__ gam,
                                                       const float* __restrict__ bet, float inv_cnt,
                                                       float* __restrict__ sc, float* __restrict__ sh) {
    int t = threadIdx.x;
    float s = ss[t], q = sq[t];
    float m = s * inv_cnt;
    float v = fmaf(q, inv_cnt, -m * m);
    v = fmaxf(v, 0.f);
    float inv = rsqrtf(v + BN_EPS);
    float scale = gam[t] * inv;
    sc[t] = scale;
    sh[t] = fmaf(-m, scale, bet[t]);
    ss[t] = 0.f;
    sq[t] = 0.f;
}

// ---------------- readout (fp32) ----------------
__global__ __launch_bounds__(256) void readout_kernel(const float* __restrict__ x,
                                                      const int* __restrict__ batch,
                                                      const float* __restrict__ sc,
                                                      const float* __restrict__ sh,
                                                      float* __restrict__ gout) {
    __shared__ int bat[256];
    int t = threadIdx.x;
    int rq = t >> 5, cq = t & 31;
    int r0 = blockIdx.x * 256;
    int i = r0 + t;
    bat[t] = (i < NN) ? batch[i] : -1;
    __syncthreads();
    float4 s4 = *(const float4*)(sc + 4 * cq);
    float4 h4 = *(const float4*)(sh + 4 * cq);
    float4 acc = make_float4(0.f, 0.f, 0.f, 0.f);
    int gcur = -1;
    for (int j = rq; j < 256; j += 8) {
        int r = r0 + j;
        if (r >= NN) break;
        int g = bat[j];
        if (g != gcur) {
            if (gcur >= 0) {
                atomicAdd(&gout[(size_t)gcur * HD + 4 * cq + 0], acc.x);
                atomicAdd(&gout[(size_t)gcur * HD + 4 * cq + 1], acc.y);
                atomicAdd(&gout[(size_t)gcur * HD + 4 * cq + 2], acc.z);
                atomicAdd(&gout[(size_t)gcur * HD + 4 * cq + 3], acc.w);
            }
            acc = make_float4(0.f, 0.f, 0.f, 0.f);
            gcur = g;
        }
        float4 v = *(const float4*)(x + (size_t)r * HD + 4 * cq);
        acc.x += fmaxf(fmaf(v.x, s4.x, h4.x), 0.f);
        acc.y += fmaxf(fmaf(v.y, s4.y, h4.y), 0.f);
        acc.z += fmaxf(fmaf(v.z, s4.z, h4.z), 0.f);
        acc.w += fmaxf(fmaf(v.w, s4.w, h4.w), 0.f);
    }
    if (gcur >= 0) {
        atomicAdd(&gout[(size_t)gcur * HD + 4 * cq + 0], acc.x);
        atomicAdd(&gout[(size_t)gcur * HD + 4 * cq + 1], acc.y);
        atomicAdd(&gout[(size_t)gcur * HD + 4 * cq + 2], acc.z);
        atomicAdd(&gout[(size_t)gcur * HD + 4 * cq + 3], acc.w);
    }
}

// ---------------- fp32 matmul for the tiny head (nrows=128) ----------------
__global__ __launch_bounds__(256) void mm_kernel(const float* __restrict__ A,
                                                 const float* __restrict__ W,
                                                 const float* __restrict__ bias,
                                                 const float* __restrict__ sc_in,
                                                 const float* __restrict__ sh_in,
                                                 float* __restrict__ out, int nrows,
                                                 float* __restrict__ stats_s,
                                                 float* __restrict__ stats_q) {
    const int PADK = 132;
    __shared__ float As[64 * PADK];
    __shared__ float colS[HD], colQ[HD];
    int t = threadIdx.x;
    if (t < HD) { colS[t] = 0.f; colQ[t] = 0.f; }
    int row0 = blockIdx.x * 64;
#pragma unroll
    for (int i = 0; i < 8; i++) {
        int idx = t + i * 256;
        int r = idx >> 5, kq = idx & 31;
        float4 v = make_float4(0.f, 0.f, 0.f, 0.f);
        int gr = row0 + r;
        if (gr < nrows) v = *(const float4*)(A + (size_t)gr * HD + 4 * kq);
        if (sc_in) {
            float4 s4 = *(const float4*)(sc_in + 4 * kq);
            float4 h4 = *(const float4*)(sh_in + 4 * kq);
            v.x = fmaxf(fmaf(v.x, s4.x, h4.x), 0.f);
            v.y = fmaxf(fmaf(v.y, s4.y, h4.y), 0.f);
            v.z = fmaxf(fmaf(v.z, s4.z, h4.z), 0.f);
            v.w = fmaxf(fmaf(v.w, s4.w, h4.w), 0.f);
        }
        *(float4*)&As[r * PADK + 4 * kq] = v;
    }
    __syncthreads();
    int jq = t & 31, rb = t >> 5;
    float acc[8][4];
#pragma unroll
    for (int i = 0; i < 8; i++)
#pragma unroll
        for (int j = 0; j < 4; j++) acc[i][j] = 0.f;
    const float* Wp = W + 4 * jq;
    const float* Ap = &As[rb * 8 * PADK];
    for (int k = 0; k < HD; k += 4) {
        float4 w0 = *(const float4*)(Wp + (size_t)(k + 0) * HD);
        float4 w1 = *(const float4*)(Wp + (size_t)(k + 1) * HD);
        float4 w2 = *(const float4*)(Wp + (size_t)(k + 2) * HD);
        float4 w3 = *(const float4*)(Wp + (size_t)(k + 3) * HD);
#pragma unroll
        for (int i = 0; i < 8; i++) {
            float4 a4 = *(const float4*)&Ap[i * PADK + k];
            acc[i][0] = fmaf(a4.x, w0.x, acc[i][0]);
            acc[i][1] = fmaf(a4.x, w0.y, acc[i][1]);
            acc[i][2] = fmaf(a4.x, w0.z, acc[i][2]);
            acc[i][3] = fmaf(a4.x, w0.w, acc[i][3]);
            acc[i][0] = fmaf(a4.y, w1.x, acc[i][0]);
            acc[i][1] = fmaf(a4.y, w1.y, acc[i][1]);
            acc[i][2] = fmaf(a4.y, w1.z, acc[i][2]);
            acc[i][3] = fmaf(a4.y, w1.w, acc[i][3]);
            acc[i][0] = fmaf(a4.z, w2.x, acc[i][0]);
            acc[i][1] = fmaf(a4.z, w2.y, acc[i][1]);
            acc[i][2] = fmaf(a4.z, w2.z, acc[i][2]);
            acc[i][3] = fmaf(a4.z, w2.w, acc[i][3]);
            acc[i][0] = fmaf(a4.w, w3.x, acc[i][0]);
            acc[i][1] = fmaf(a4.w, w3.y, acc[i][1]);
            acc[i][2] = fmaf(a4.w, w3.z, acc[i][2]);
            acc[i][3] = fmaf(a4.w, w3.w, acc[i][3]);
        }
    }
    float4 b4 = make_float4(0.f, 0.f, 0.f, 0.f);
    if (bias) b4 = *(const float4*)(bias + 4 * jq);
    float s0 = 0, s1 = 0, s2 = 0, s3 = 0, q0 = 0, q1 = 0, q2 = 0, q3 = 0;
#pragma unroll
    for (int i = 0; i < 8; i++) {
        int gr = row0 + rb * 8 + i;
        if (gr < nrows) {
            float4 v;
            v.x = acc[i][0] + b4.x;
            v.y = acc[i][1] + b4.y;
            v.z = acc[i][2] + b4.z;
            v.w = acc[i][3] + b4.w;
            *(float4*)(out + (size_t)gr * HD + 4 * jq) = v;
            s0 += v.x; q0 += v.x * v.x;
            s1 += v.y; q1 += v.y * v.y;
            s2 += v.z; q2 += v.z * v.z;
            s3 += v.w; q3 += v.w * v.w;
        }
    }
    atomicAdd(&colS[4 * jq + 0], s0); atomicAdd(&colQ[4 * jq + 0], q0);
    atomicAdd(&colS[4 * jq + 1], s1); atomicAdd(&colQ[4 * jq + 1], q1);
    atomicAdd(&colS[4 * jq + 2], s2); atomicAdd(&colQ[4 * jq + 2], q2);
    atomicAdd(&colS[4 * jq + 3], s3); atomicAdd(&colQ[4 * jq + 3], q3);
    __syncthreads();
    if (t < HD) {
        atomicAdd(&stats_s[t], colS[t]);
        atomicAdd(&stats_q[t], colQ[t]);
    }
}

// ---------------- final: out[g] = act(h[g]) . fin_W ----------------
__global__ __launch_bounds__(128) void final_kernel(const float* __restrict__ h,
                                                    const float* __restrict__ sc,
                                                    const float* __restrict__ sh,
                                                    const float* __restrict__ finW,
                                                    float* __restrict__ out) {
    int t = threadIdx.x;
    float s = 0.f;
    for (int c = 0; c < HD; c++) {
        float v = h[(size_t)t * HD + c];
        v = fmaxf(fmaf(v, sc[c], sh[c]), 0.f);
        s += v * finW[c];
    }
    out[t] = s;
}

extern "C" void kernel_launch(void* const* d_in, const int* in_sizes, int n_in,
                              void* d_out, int out_size, void* d_ws, size_t ws_size,
                              hipStream_t stream) {
    const int* x_ids = (const int*)d_in[0];
    const int* edge_index = (const int*)d_in[1];
    const int* batch = (const int*)d_in[2];
    const int* edge_attr = (const int*)d_in[3];
    const float* node_emb = (const float*)d_in[4];
    const float* edge_emb = (const float*)d_in[5];
    const float* eps = (const float*)d_in[6];
    const float* init_W1 = (const float*)d_in[7];
    const float* init_b1 = (const float*)d_in[8];
    const float* init_g1 = (const float*)d_in[9];
    const float* init_be1 = (const float*)d_in[10];
    const float* init_W2 = (const float*)d_in[11];
    const float* init_b2 = (const float*)d_in[12];
    const float* init_g2 = (const float*)d_in[13];
    const float* init_be2 = (const float*)d_in[14];
    const float* mp_W1 = (const float*)d_in[15];
    const float* mp_g1 = (const float*)d_in[16];
    const float* mp_be1 = (const float*)d_in[17];
    const float* mp_W2 = (const float*)d_in[18];
    const float* mp_g2 = (const float*)d_in[19];
    const float* mp_be2 = (const float*)d_in[20];
    const float* l1_W1 = (const float*)d_in[21];
    const float* l1_g1 = (const float*)d_in[22];
    const float* l1_b1 = (const float*)d_in[23];
    const float* l1_W2 = (const float*)d_in[24];
    const float* l1_g2 = (const float*)d_in[25];
    const float* l1_b2 = (const float*)d_in[26];
    const float* l2_W1 = (const float*)d_in[27];
    const float* l2_g1 = (const float*)d_in[28];
    const float* l2_b1 = (const float*)d_in[29];
    const float* l2_W2 = (const float*)d_in[30];
    const float* l2_g2 = (const float*)d_in[31];
    const float* l2_b2 = (const float*)d_in[32];
    const float* fin_W = (const float*)d_in[33];

    const int* e_src = edge_index;
    const int* e_dst = edge_index + NE;

    // workspace layout (floats)
    float* ws = (float*)d_ws;
    float* X = ws;                       // 50000*128
    float* Abuf = X + (size_t)NN * HD;
    float* Bbuf = Abuf + (size_t)NN * HD;
    float* Gp = Bbuf + (size_t)NN * HD;  // 128*128
    float* Hp = Gp + NG * HD;
    float* Hp2 = Hp + NG * HD;
    float* S1 = Hp2 + NG * HD;           // 128
    float* Q1 = S1 + HD;
    float* scA = Q1 + HD;
    float* shA = scA + HD;
    float* scB = shA + HD;
    float* shB = scB + HD;
    int* rowptr = (int*)(shB + HD);      // 50001 -> pad 50048
    int* cursor = rowptr + 50048;
    int* deg = cursor + 50048;
    int* blockSum = deg + 50048;         // 64
    int* blockOff = blockSum + 64;       // 64
    unsigned* csr = (unsigned*)(blockOff + 64);      // 800000
    unsigned short* Wh = (unsigned short*)(csr + NE);  // 163840 bf16
    unsigned short* Wl = Wh + 163840;                  // 163840 bf16

    hipMemsetAsync(deg, 0, NN * sizeof(int), stream);
    hipMemsetAsync(S1, 0, 2 * HD * sizeof(float), stream);
    hipMemsetAsync(Gp, 0, NG * HD * sizeof(float), stream);

    const int SCAN_BLOCKS = (NN + 1023) / 1024;  // 49
    embed_kernel<<<(NN * 32) / 256, 256, 0, stream>>>(x_ids, node_emb, X);
    cvtw_kernel<<<640, 256, 0, stream>>>(init_W1, init_W2, mp_W1, mp_W2, Wh, Wl);
    hist_kernel<<<(NE + 255) / 256, 256, 0, stream>>>(e_dst, deg);
    scan1_kernel<<<SCAN_BLOCKS, 1024, 0, stream>>>(deg, rowptr, blockSum);
    scan2_kernel<<<1, 64, 0, stream>>>(blockSum, blockOff, rowptr, SCAN_BLOCKS);
    scan3_kernel<<<SCAN_BLOCKS, 1024, 0, stream>>>(rowptr, cursor, blockOff);
    scatter_kernel<<<(NE + 255) / 256, 256, 0, stream>>>(e_src, e_dst, edge_attr, cursor, csr);

    const int mfma_grid = (NN + 127) / 128;  // 391
    for (int i = 0; i <= NL; i++) {
        const unsigned short* Wh1 = Wh + (i == 0 ? 0 : 32768 + (i - 1) * 16384);
        const unsigned short* Wl1 = Wl + (i == 0 ? 0 : 32768 + (i - 1) * 16384);
        const unsigned short* Wh2 = Wh + (i == 0 ? 16384 : 98304 + (i - 1) * 16384);
        const unsigned short* Wl2 = Wl + (i == 0 ? 16384 : 98304 + (i - 1) * 16384);
        const float* b1 = (i == 0) ? init_b1 : nullptr;
        const float* b2 = (i == 0) ? init_b2 : nullptr;
        const float* g1 = (i == 0) ? init_g1 : mp_g1 + (size_t)(i - 1) * HD;
        const float* be1 = (i == 0) ? init_be1 : mp_be1 + (size_t)(i - 1) * HD;
        const float* g2 = (i == 0) ? init_g2 : mp_g2 + (size_t)(i - 1) * HD;
        const float* be2 = (i == 0) ? init_be2 : mp_be2 + (size_t)(i - 1) * HD;

        conv_kernel<<<(NN + 3) / 4, 256, 0, stream>>>(X, rowptr, csr, edge_emb, eps, i, scB,
                                                      shB, (i > 0) ? 1 : 0, Abuf);
        mm_mfma<<<mfma_grid, 256, 0, stream>>>(Abuf, Wh1, Wl1, b1, nullptr, nullptr, Bbuf, S1, Q1);
        finalize_kernel<<<1, 128, 0, stream>>>(S1, Q1, g1, be1, 1.f / NN, scA, shA);
        mm_mfma<<<mfma_grid, 256, 0, stream>>>(Bbuf, Wh2, Wl2, b2, scA, shA, X, S1, Q1);
        finalize_kernel<<<1, 128, 0, stream>>>(S1, Q1, g2, be2, 1.f / NN, scB, shB);
    }

    readout_kernel<<<(NN + 255) / 256, 256, 0, stream>>>(X, batch, scB, shB, Gp);

    // head (fp32, tiny)
    mm_kernel<<<2, 256, 0, stream>>>(Gp, l1_W1, nullptr, nullptr, nullptr, Hp, NG, S1, Q1);
    finalize_kernel<<<1, 128, 0, stream>>>(S1, Q1, l1_g1, l1_b1, 1.f / NG, scA, shA);
    mm_kernel<<<2, 256, 0, stream>>>(Hp, l1_W2, nullptr, scA, shA, Hp2, NG, S1, Q1);
    finalize_kernel<<<1, 128, 0, stream>>>(S1, Q1, l1_g2, l1_b2, 1.f / NG, scB, shB);
    mm_kernel<<<2, 256, 0, stream>>>(Hp2, l2_W1, nullptr, scB, shB, Hp, NG, S1, Q1);
    finalize_kernel<<<1, 128, 0, stream>>>(S1, Q1, l2_g1, l2_b1, 1.f / NG, scA, shA);
    mm_kernel<<<2, 256, 0, stream>>>(Hp, l2_W2, nullptr, scA, shA, Hp2, NG, S1, Q1);
    finalize_kernel<<<1, 128, 0, stream>>>(S1, Q1, l2_g2, l2_b2, 1.f / NG, scB, shB);

    final_kernel<<<1, 128, 0, stream>>>(Hp2, scB, shB, fin_W, (float*)d_out);
}

// Round 6
// 987.223 us; speedup vs baseline: 1.4758x; 1.0294x over previous
//
#include <hip/hip_runtime.h>

#define NN 50000
#define NE 800000
#define NG 128
#define HD 128
#define NL 4
#define BN_EPS 1e-5f

typedef __attribute__((ext_vector_type(8))) short bf16x8;
typedef __attribute__((ext_vector_type(4))) float f32x4;

__device__ __forceinline__ unsigned short f2bf(float f) {
    unsigned u = __float_as_uint(f);
    u += 0x7FFFu + ((u >> 16) & 1u);  // RNE
    return (unsigned short)(u >> 16);
}
__device__ __forceinline__ float bfval(unsigned short h) { return __uint_as_float((unsigned)h << 16); }

// split pair (a,b) -> packed hi (truncated bf16) and lo (RNE bf16 of residual)
__device__ __forceinline__ void split2(float a, float b, unsigned& hi, unsigned& lo) {
    unsigned ua = __float_as_uint(a), ub = __float_as_uint(b);
    hi = (ua >> 16) | (ub & 0xFFFF0000u);
    float ra = a - __uint_as_float(ua & 0xFFFF0000u);
    float rb = b - __uint_as_float(ub & 0xFFFF0000u);
    lo = (unsigned)f2bf(ra) | ((unsigned)f2bf(rb) << 16);
}

__device__ __forceinline__ void bn_to_scale(const float* S, const float* Q,
                                            const float* gam, const float* bet,
                                            float inv_cnt, int t, float* scs, float* shs) {
    float m = S[t] * inv_cnt;
    float var = fmaxf(fmaf(Q[t], inv_cnt, -m * m), 0.f);
    float inv = rsqrtf(var + BN_EPS);
    float sc = gam[t] * inv;
    scs[t] = sc;
    shs[t] = fmaf(-m, sc, bet[t]);
}

// ---------------- embed: x[n] = node_emb[x_ids[n]] (fp32) ----------------
__global__ __launch_bounds__(256) void embed_kernel(const int* __restrict__ ids,
                                                    const float* __restrict__ emb,
                                                    float* __restrict__ x) {
    int i = blockIdx.x * 256 + threadIdx.x;
    if (i < NN * 32) {
        int node = i >> 5, q = i & 31;
        int id = ids[node];
        float4 v = *(const float4*)(emb + (size_t)id * HD + 4 * q);
        *(float4*)(x + (size_t)node * HD + 4 * q) = v;
    }
}

// ---------------- weight convert: split W[k][n] fp32 -> Wh/Wl bf16 [n][k] ----------------
// segments of 16384: 0=iW1 1=iW2 2..5=mpW1 6..9=mpW2 10=l1W1 11=l1W2 12=l2W1 13=l2W2
__global__ __launch_bounds__(256) void cvtw_kernel(const float* __restrict__ iw1,
                                                   const float* __restrict__ iw2,
                                                   const float* __restrict__ mw1,
                                                   const float* __restrict__ mw2,
                                                   const float* __restrict__ l1w1,
                                                   const float* __restrict__ l1w2,
                                                   const float* __restrict__ l2w1,
                                                   const float* __restrict__ l2w2,
                                                   unsigned short* __restrict__ Wh,
                                                   unsigned short* __restrict__ Wl) {
    int i = blockIdx.x * 256 + threadIdx.x;  // 229376 total
    if (i >= 229376) return;
    int seg = i >> 14, loc = i & 16383;
    float v;
    if (seg == 0)      v = iw1[loc];
    else if (seg == 1) v = iw2[loc];
    else if (seg < 6)  v = mw1[(seg - 2) * 16384 + loc];
    else if (seg < 10) v = mw2[(seg - 6) * 16384 + loc];
    else if (seg == 10) v = l1w1[loc];
    else if (seg == 11) v = l1w2[loc];
    else if (seg == 12) v = l2w1[loc];
    else                v = l2w2[loc];
    int k = loc >> 7, n = loc & 127;
    unsigned short h = f2bf(v);
    float r = v - bfval(h);
    Wh[seg * 16384 + n * 128 + k] = h;
    Wl[seg * 16384 + n * 128 + k] = f2bf(r);
}

// ---------------- CSR build ----------------
__global__ __launch_bounds__(256) void hist_kernel(const int* __restrict__ dst,
                                                   int* __restrict__ deg) {
    int e = blockIdx.x * 256 + threadIdx.x;
    if (e < NE) atomicAdd(&deg[dst[e]], 1);
}

__global__ __launch_bounds__(1024) void scan1_kernel(const int* __restrict__ deg,
                                                     int* __restrict__ rowptr,
                                                     int* __restrict__ blockSum) {
    __shared__ int s[1024];
    int b = blockIdx.x, t = threadIdx.x;
    int i = b * 1024 + t;
    int v = (i < NN) ? deg[i] : 0;
    s[t] = v;
    __syncthreads();
    for (int off = 1; off < 1024; off <<= 1) {
        int u = (t >= off) ? s[t - off] : 0;
        __syncthreads();
        s[t] += u;
        __syncthreads();
    }
    if (i < NN) rowptr[i] = s[t] - v;
    if (t == 1023) blockSum[b] = s[1023];
}

__global__ __launch_bounds__(64) void scan2_kernel(const int* __restrict__ blockSum,
                                                   int* __restrict__ blockOff,
                                                   int* __restrict__ rowptr, int nblocks) {
    int t = threadIdx.x;
    int orig = (t < nblocks) ? blockSum[t] : 0;
    int v = orig;
    for (int off = 1; off < 64; off <<= 1) {
        int u = __shfl_up(v, off, 64);
        if (t >= off) v += u;
    }
    if (t < nblocks) blockOff[t] = v - orig;
    if (t == nblocks - 1) rowptr[NN] = v;
}

__global__ __launch_bounds__(1024) void scan3_kernel(int* __restrict__ rowptr,
                                                     int* __restrict__ cursor,
                                                     const int* __restrict__ blockOff) {
    int b = blockIdx.x, t = threadIdx.x;
    int i = b * 1024 + t;
    if (i < NN) {
        int r = rowptr[i] + blockOff[b];
        rowptr[i] = r;
        cursor[i] = r;
    }
}

__global__ __launch_bounds__(256) void scatter_kernel(const int* __restrict__ src,
                                                      const int* __restrict__ dst,
                                                      const int* __restrict__ attr,
                                                      int* __restrict__ cursor,
                                                      unsigned* __restrict__ csr) {
    int e = blockIdx.x * 256 + threadIdx.x;
    if (e < NE) {
        int d = dst[e];
        int pos = atomicAdd(&cursor[d], 1);
        csr[pos] = (unsigned)src[e] | ((unsigned)attr[e] << 16);
    }
}

// ---------------- GINE conv (fp32 gather) -> writes split bf16 hi/lo planes ----------------
__global__ __launch_bounds__(256) void conv_kernel(const float* __restrict__ x,
                                                   const int* __restrict__ rowptr,
                                                   const unsigned* __restrict__ csr,
                                                   const float* __restrict__ edge_emb,
                                                   const float* __restrict__ eps, int layer,
                                                   const float* __restrict__ Sin,
                                                   const float* __restrict__ Qin,
                                                   const float* __restrict__ gam,
                                                   const float* __restrict__ bet, int apply_act,
                                                   unsigned short* __restrict__ Ah,
                                                   unsigned short* __restrict__ Al) {
    __shared__ float elds[8 * HD];
    __shared__ float scs[HD], shs[HD];
    int t = threadIdx.x;
    ((float4*)elds)[t] = ((const float4*)edge_emb)[t];
    if (apply_act && t < HD) bn_to_scale(Sin, Qin, gam, bet, 1.f / NN, t, scs, shs);
    __syncthreads();
    int wave = t >> 6, lane = t & 63;
    int node = blockIdx.x * 4 + wave;
    if (node >= NN) return;
    int sub = lane >> 5;
    int cq = lane & 31;
    int lo = rowptr[node], hi = rowptr[node + 1];
    float4 s4 = make_float4(1.f, 1.f, 1.f, 1.f);
    float4 h4 = make_float4(0.f, 0.f, 0.f, 0.f);
    if (apply_act) {
        s4 = *(const float4*)&scs[4 * cq];
        h4 = *(const float4*)&shs[4 * cq];
    }
    float4 acc = make_float4(0.f, 0.f, 0.f, 0.f);
    for (int base = lo; base < hi; base += 64) {
        unsigned pl = 0;
        int cnt = hi - base; if (cnt > 64) cnt = 64;
        if (base + lane < hi) pl = csr[base + lane];
        int j = 0;
        for (; j + 4 <= cnt; j += 4) {
            unsigned pa = __shfl(pl, j + sub, 64);
            unsigned pb = __shfl(pl, j + 2 + sub, 64);
            float4 xa = *(const float4*)(x + (size_t)(pa & 0xFFFFu) * HD + 4 * cq);
            float4 xb = *(const float4*)(x + (size_t)(pb & 0xFFFFu) * HD + 4 * cq);
            float4 ea = *(const float4*)&elds[(pa >> 16) * HD + 4 * cq];
            float4 eb = *(const float4*)&elds[(pb >> 16) * HD + 4 * cq];
            if (apply_act) {
                xa.x = fmaxf(fmaf(xa.x, s4.x, h4.x), 0.f);
                xa.y = fmaxf(fmaf(xa.y, s4.y, h4.y), 0.f);
                xa.z = fmaxf(fmaf(xa.z, s4.z, h4.z), 0.f);
                xa.w = fmaxf(fmaf(xa.w, s4.w, h4.w), 0.f);
                xb.x = fmaxf(fmaf(xb.x, s4.x, h4.x), 0.f);
                xb.y = fmaxf(fmaf(xb.y, s4.y, h4.y), 0.f);
                xb.z = fmaxf(fmaf(xb.z, s4.z, h4.z), 0.f);
                xb.w = fmaxf(fmaf(xb.w, s4.w, h4.w), 0.f);
            }
            acc.x += fmaxf(xa.x + ea.x, 0.f) + fmaxf(xb.x + eb.x, 0.f);
            acc.y += fmaxf(xa.y + ea.y, 0.f) + fmaxf(xb.y + eb.y, 0.f);
            acc.z += fmaxf(xa.z + ea.z, 0.f) + fmaxf(xb.z + eb.z, 0.f);
            acc.w += fmaxf(xa.w + ea.w, 0.f) + fmaxf(xb.w + eb.w, 0.f);
        }
        for (; j < cnt; j += 2) {
            int je = j + sub;
            int valid = (je < cnt);
            unsigned p = __shfl(pl, valid ? je : j, 64);
            float4 xa = *(const float4*)(x + (size_t)(p & 0xFFFFu) * HD + 4 * cq);
            float4 ea = *(const float4*)&elds[(p >> 16) * HD + 4 * cq];
            if (apply_act) {
                xa.x = fmaxf(fmaf(xa.x, s4.x, h4.x), 0.f);
                xa.y = fmaxf(fmaf(xa.y, s4.y, h4.y), 0.f);
                xa.z = fmaxf(fmaf(xa.z, s4.z, h4.z), 0.f);
                xa.w = fmaxf(fmaf(xa.w, s4.w, h4.w), 0.f);
            }
            float m = valid ? 1.f : 0.f;
            acc.x += m * fmaxf(xa.x + ea.x, 0.f);
            acc.y += m * fmaxf(xa.y + ea.y, 0.f);
            acc.z += m * fmaxf(xa.z + ea.z, 0.f);
            acc.w += m * fmaxf(xa.w + ea.w, 0.f);
        }
    }
    acc.x += __shfl_xor(acc.x, 32, 64);
    acc.y += __shfl_xor(acc.y, 32, 64);
    acc.z += __shfl_xor(acc.z, 32, 64);
    acc.w += __shfl_xor(acc.w, 32, 64);
    if (sub == 0) {
        float ep = eps[layer];
        float4 xs = *(const float4*)(x + (size_t)node * HD + 4 * cq);
        if (apply_act) {
            xs.x = fmaxf(fmaf(xs.x, s4.x, h4.x), 0.f);
            xs.y = fmaxf(fmaf(xs.y, s4.y, h4.y), 0.f);
            xs.z = fmaxf(fmaf(xs.z, s4.z, h4.z), 0.f);
            xs.w = fmaxf(fmaf(xs.w, s4.w, h4.w), 0.f);
        }
        float4 o;
        o.x = (1.f + ep) * xs.x + acc.x;
        o.y = (1.f + ep) * xs.y + acc.y;
        o.z = (1.f + ep) * xs.z + acc.z;
        o.w = (1.f + ep) * xs.w + acc.w;
        unsigned h0, l0, h1, l1;
        split2(o.x, o.y, h0, l0);
        split2(o.z, o.w, h1, l1);
        *(uint2*)(Ah + (size_t)node * HD + 4 * cq) = make_uint2(h0, h1);
        *(uint2*)(Al + (size_t)node * HD + 4 * cq) = make_uint2(l0, l1);
    }
}

// ---------------- MFMA matmul, pre-split A (hi/lo bf16 planes), no input act ----------------
// Block 256 = 4 waves covering 128 rows; wave -> 32 rows (2 tiles of 16) x 128 cols (8 tiles).
__global__ __launch_bounds__(256) void mm_mfma_pre(const unsigned short* __restrict__ Ah,
                                                   const unsigned short* __restrict__ Al,
                                                   const unsigned short* __restrict__ Wh,
                                                   const unsigned short* __restrict__ Wl,
                                                   const float* __restrict__ bias,
                                                   float* __restrict__ out,
                                                   float* __restrict__ Sout,
                                                   float* __restrict__ Qout) {
    __shared__ float colS[HD], colQ[HD];
    int t = threadIdx.x;
    if (t < HD) { colS[t] = 0.f; colQ[t] = 0.f; }
    __syncthreads();
    int w = t >> 6, lane = t & 63;
    int quad = lane >> 4, nl = lane & 15;
    int row0 = blockIdx.x * 128 + w * 32;
    int rA0 = row0 + nl, rA1 = row0 + 16 + nl;
    bool ok0 = rA0 < NN, ok1 = rA1 < NN;
    f32x4 acc[16];
#pragma unroll
    for (int i = 0; i < 16; i++) acc[i] = (f32x4){0.f, 0.f, 0.f, 0.f};
#pragma unroll
    for (int kc = 0; kc < 4; kc++) {
        int k0 = kc * 32 + quad * 8;
        bf16x8 a0h = ok0 ? *(const bf16x8*)(Ah + (size_t)rA0 * HD + k0) : (bf16x8)0;
        bf16x8 a0l = ok0 ? *(const bf16x8*)(Al + (size_t)rA0 * HD + k0) : (bf16x8)0;
        bf16x8 a1h = ok1 ? *(const bf16x8*)(Ah + (size_t)rA1 * HD + k0) : (bf16x8)0;
        bf16x8 a1l = ok1 ? *(const bf16x8*)(Al + (size_t)rA1 * HD + k0) : (bf16x8)0;
#pragma unroll
        for (int c = 0; c < 8; c++) {
            size_t widx = (size_t)(c * 16 + nl) * HD + k0;
            bf16x8 bh = *(const bf16x8*)(Wh + widx);
            bf16x8 bl = *(const bf16x8*)(Wl + widx);
            acc[c] = __builtin_amdgcn_mfma_f32_16x16x32_bf16(a0h, bh, acc[c], 0, 0, 0);
            acc[c] = __builtin_amdgcn_mfma_f32_16x16x32_bf16(a0l, bh, acc[c], 0, 0, 0);
            acc[c] = __builtin_amdgcn_mfma_f32_16x16x32_bf16(a0h, bl, acc[c], 0, 0, 0);
            acc[8 + c] = __builtin_amdgcn_mfma_f32_16x16x32_bf16(a1h, bh, acc[8 + c], 0, 0, 0);
            acc[8 + c] = __builtin_amdgcn_mfma_f32_16x16x32_bf16(a1l, bh, acc[8 + c], 0, 0, 0);
            acc[8 + c] = __builtin_amdgcn_mfma_f32_16x16x32_bf16(a1h, bl, acc[8 + c], 0, 0, 0);
        }
    }
#pragma unroll
    for (int h = 0; h < 2; h++) {
        int baserow = row0 + h * 16 + quad * 4;
#pragma unroll
        for (int c = 0; c < 8; c++) {
            int col = c * 16 + nl;
            float bv = bias ? bias[col] : 0.f;
            f32x4 v = acc[h * 8 + c];
            float s = 0.f, qq = 0.f;
#pragma unroll
            for (int r = 0; r < 4; r++) {
                int gr = baserow + r;
                float val = v[r] + bv;
                if (gr < NN) {
                    out[(size_t)gr * HD + col] = val;
                    s += val;
                    qq += val * val;
                }
            }
            s += __shfl_xor(s, 16, 64);  s += __shfl_xor(s, 32, 64);
            qq += __shfl_xor(qq, 16, 64); qq += __shfl_xor(qq, 32, 64);
            if (quad == 0) {
                atomicAdd(&colS[col], s);
                atomicAdd(&colQ[col], qq);
            }
        }
    }
    __syncthreads();
    if (t < HD) {
        atomicAdd(&Sout[t], colS[t]);
        atomicAdd(&Qout[t], colQ[t]);
    }
}

// ---------------- MFMA matmul, fp32 A with fused BN-act, in-register split ----------------
__global__ __launch_bounds__(256) void mm_mfma_act(const float* __restrict__ A,
                                                   const unsigned short* __restrict__ Wh,
                                                   const unsigned short* __restrict__ Wl,
                                                   const float* __restrict__ bias,
                                                   const float* __restrict__ Sin,
                                                   const float* __restrict__ Qin,
                                                   const float* __restrict__ gam,
                                                   const float* __restrict__ bet,
                                                   float* __restrict__ out,
                                                   float* __restrict__ Sout,
                                                   float* __restrict__ Qout) {
    __shared__ float colS[HD], colQ[HD];
    __shared__ float scs[HD], shs[HD];
    int t = threadIdx.x;
    if (t < HD) {
        colS[t] = 0.f; colQ[t] = 0.f;
        bn_to_scale(Sin, Qin, gam, bet, 1.f / NN, t, scs, shs);
    }
    __syncthreads();
    int w = t >> 6, lane = t & 63;
    int quad = lane >> 4, nl = lane & 15;
    int row0 = blockIdx.x * 128 + w * 32;
    int rA0 = row0 + nl, rA1 = row0 + 16 + nl;
    bool ok0 = rA0 < NN, ok1 = rA1 < NN;
    f32x4 acc[16];
#pragma unroll
    for (int i = 0; i < 16; i++) acc[i] = (f32x4){0.f, 0.f, 0.f, 0.f};
#pragma unroll
    for (int kc = 0; kc < 4; kc++) {
        int k0 = kc * 32 + quad * 8;
        float4 s0 = *(const float4*)&scs[k0], s1 = *(const float4*)&scs[k0 + 4];
        float4 t0 = *(const float4*)&shs[k0], t1 = *(const float4*)&shs[k0 + 4];
        bf16x8 a0h, a0l, a1h, a1l;
        {
            float4 v0 = ok0 ? *(const float4*)(A + (size_t)rA0 * HD + k0) : make_float4(0, 0, 0, 0);
            float4 v1 = ok0 ? *(const float4*)(A + (size_t)rA0 * HD + k0 + 4) : make_float4(0, 0, 0, 0);
            float f0 = fmaxf(fmaf(v0.x, s0.x, t0.x), 0.f), f1 = fmaxf(fmaf(v0.y, s0.y, t0.y), 0.f);
            float f2 = fmaxf(fmaf(v0.z, s0.z, t0.z), 0.f), f3 = fmaxf(fmaf(v0.w, s0.w, t0.w), 0.f);
            float f4 = fmaxf(fmaf(v1.x, s1.x, t1.x), 0.f), f5 = fmaxf(fmaf(v1.y, s1.y, t1.y), 0.f);
            float f6 = fmaxf(fmaf(v1.z, s1.z, t1.z), 0.f), f7 = fmaxf(fmaf(v1.w, s1.w, t1.w), 0.f);
            unsigned h0, h1, h2, h3, l0, l1, l2, l3;
            split2(f0, f1, h0, l0); split2(f2, f3, h1, l1);
            split2(f4, f5, h2, l2); split2(f6, f7, h3, l3);
            a0h = __builtin_bit_cast(bf16x8, make_uint4(h0, h1, h2, h3));
            a0l = __builtin_bit_cast(bf16x8, make_uint4(l0, l1, l2, l3));
        }
        {
            float4 v0 = ok1 ? *(const float4*)(A + (size_t)rA1 * HD + k0) : make_float4(0, 0, 0, 0);
            float4 v1 = ok1 ? *(const float4*)(A + (size_t)rA1 * HD + k0 + 4) : make_float4(0, 0, 0, 0);
            float f0 = fmaxf(fmaf(v0.x, s0.x, t0.x), 0.f), f1 = fmaxf(fmaf(v0.y, s0.y, t0.y), 0.f);
            float f2 = fmaxf(fmaf(v0.z, s0.z, t0.z), 0.f), f3 = fmaxf(fmaf(v0.w, s0.w, t0.w), 0.f);
            float f4 = fmaxf(fmaf(v1.x, s1.x, t1.x), 0.f), f5 = fmaxf(fmaf(v1.y, s1.y, t1.y), 0.f);
            float f6 = fmaxf(fmaf(v1.z, s1.z, t1.z), 0.f), f7 = fmaxf(fmaf(v1.w, s1.w, t1.w), 0.f);
            unsigned h0, h1, h2, h3, l0, l1, l2, l3;
            split2(f0, f1, h0, l0); split2(f2, f3, h1, l1);
            split2(f4, f5, h2, l2); split2(f6, f7, h3, l3);
            a1h = __builtin_bit_cast(bf16x8, make_uint4(h0, h1, h2, h3));
            a1l = __builtin_bit_cast(bf16x8, make_uint4(l0, l1, l2, l3));
        }
#pragma unroll
        for (int c = 0; c < 8; c++) {
            size_t widx = (size_t)(c * 16 + nl) * HD + k0;
            bf16x8 bh = *(const bf16x8*)(Wh + widx);
            bf16x8 bl = *(const bf16x8*)(Wl + widx);
            acc[c] = __builtin_amdgcn_mfma_f32_16x16x32_bf16(a0h, bh, acc[c], 0, 0, 0);
            acc[c] = __builtin_amdgcn_mfma_f32_16x16x32_bf16(a0l, bh, acc[c], 0, 0, 0);
            acc[c] = __builtin_amdgcn_mfma_f32_16x16x32_bf16(a0h, bl, acc[c], 0, 0, 0);
            acc[8 + c] = __builtin_amdgcn_mfma_f32_16x16x32_bf16(a1h, bh, acc[8 + c], 0, 0, 0);
            acc[8 + c] = __builtin_amdgcn_mfma_f32_16x16x32_bf16(a1l, bh, acc[8 + c], 0, 0, 0);
            acc[8 + c] = __builtin_amdgcn_mfma_f32_16x16x32_bf16(a1h, bl, acc[8 + c], 0, 0, 0);
        }
    }
#pragma unroll
    for (int h = 0; h < 2; h++) {
        int baserow = row0 + h * 16 + quad * 4;
#pragma unroll
        for (int c = 0; c < 8; c++) {
            int col = c * 16 + nl;
            float bv = bias ? bias[col] : 0.f;
            f32x4 v = acc[h * 8 + c];
            float s = 0.f, qq = 0.f;
#pragma unroll
            for (int r = 0; r < 4; r++) {
                int gr = baserow + r;
                float val = v[r] + bv;
                if (gr < NN) {
                    out[(size_t)gr * HD + col] = val;
                    s += val;
                    qq += val * val;
                }
            }
            s += __shfl_xor(s, 16, 64);  s += __shfl_xor(s, 32, 64);
            qq += __shfl_xor(qq, 16, 64); qq += __shfl_xor(qq, 32, 64);
            if (quad == 0) {
                atomicAdd(&colS[col], s);
                atomicAdd(&colQ[col], qq);
            }
        }
    }
    __syncthreads();
    if (t < HD) {
        atomicAdd(&Sout[t], colS[t]);
        atomicAdd(&Qout[t], colQ[t]);
    }
}

// ---------------- readout: Gp[g] += sum act(X) over nodes ----------------
__global__ __launch_bounds__(256) void readout_kernel(const float* __restrict__ x,
                                                      const int* __restrict__ batch,
                                                      const float* __restrict__ Sin,
                                                      const float* __restrict__ Qin,
                                                      const float* __restrict__ gam,
                                                      const float* __restrict__ bet,
                                                      float* __restrict__ gout) {
    __shared__ int bat[256];
    __shared__ float scs[HD], shs[HD];
    int t = threadIdx.x;
    int rq = t >> 5, cq = t & 31;
    int r0 = blockIdx.x * 256;
    int i = r0 + t;
    bat[t] = (i < NN) ? batch[i] : -1;
    if (t < HD) bn_to_scale(Sin, Qin, gam, bet, 1.f / NN, t, scs, shs);
    __syncthreads();
    float4 s4 = *(const float4*)&scs[4 * cq];
    float4 h4 = *(const float4*)&shs[4 * cq];
    float4 acc = make_float4(0.f, 0.f, 0.f, 0.f);
    int gcur = -1;
    for (int j = rq; j < 256; j += 8) {
        int r = r0 + j;
        if (r >= NN) break;
        int g = bat[j];
        if (g != gcur) {
            if (gcur >= 0) {
                atomicAdd(&gout[(size_t)gcur * HD + 4 * cq + 0], acc.x);
                atomicAdd(&gout[(size_t)gcur * HD + 4 * cq + 1], acc.y);
                atomicAdd(&gout[(size_t)gcur * HD + 4 * cq + 2], acc.z);
                atomicAdd(&gout[(size_t)gcur * HD + 4 * cq + 3], acc.w);
            }
            acc = make_float4(0.f, 0.f, 0.f, 0.f);
            gcur = g;
        }
        float4 v = *(const float4*)(x + (size_t)r * HD + 4 * cq);
        acc.x += fmaxf(fmaf(v.x, s4.x, h4.x), 0.f);
        acc.y += fmaxf(fmaf(v.y, s4.y, h4.y), 0.f);
        acc.z += fmaxf(fmaf(v.z, s4.z, h4.z), 0.f);
        acc.w += fmaxf(fmaf(v.w, s4.w, h4.w), 0.f);
    }
    if (gcur >= 0) {
        atomicAdd(&gout[(size_t)gcur * HD + 4 * cq + 0], acc.x);
        atomicAdd(&gout[(size_t)gcur * HD + 4 * cq + 1], acc.y);
        atomicAdd(&gout[(size_t)gcur * HD + 4 * cq + 2], acc.z);
        atomicAdd(&gout[(size_t)gcur * HD + 4 * cq + 3], acc.w);
    }
}

// ---------------- fused head: 4x (matmul + BN + relu) + final dot, one block ----------------
__global__ __launch_bounds__(512) void head_kernel(const float* __restrict__ Gp,
                                                   const unsigned short* __restrict__ WhH,
                                                   const unsigned short* __restrict__ WlH,
                                                   const float* __restrict__ g0, const float* __restrict__ b0,
                                                   const float* __restrict__ g1, const float* __restrict__ b1,
                                                   const float* __restrict__ g2, const float* __restrict__ b2,
                                                   const float* __restrict__ g3, const float* __restrict__ b3,
                                                   const float* __restrict__ finW,
                                                   float* __restrict__ out) {
    const int YP = 132;
    __shared__ float Y[128 * YP];
    __shared__ float S[128], Q[128], scs[128], shs[128];
    int t = threadIdx.x;
    int w = t >> 6, lane = t & 63, quad = lane >> 4, nl = lane & 15;
    int rrow = w * 16 + nl;
    const float* gs[4] = {g0, g1, g2, g3};
    const float* bs[4] = {b0, b1, b2, b3};
    for (int L = 0; L < 4; L++) {
        const unsigned short* wh = WhH + (size_t)L * 16384;
        const unsigned short* wl = WlH + (size_t)L * 16384;
        f32x4 acc[8];
#pragma unroll
        for (int i = 0; i < 8; i++) acc[i] = (f32x4){0.f, 0.f, 0.f, 0.f};
#pragma unroll
        for (int kc = 0; kc < 4; kc++) {
            int k0 = kc * 32 + quad * 8;
            float f0, f1, f2, f3, f4, f5, f6, f7;
            if (L == 0) {
                float4 v0 = *(const float4*)(Gp + (size_t)rrow * HD + k0);
                float4 v1 = *(const float4*)(Gp + (size_t)rrow * HD + k0 + 4);
                f0 = v0.x; f1 = v0.y; f2 = v0.z; f3 = v0.w;
                f4 = v1.x; f5 = v1.y; f6 = v1.z; f7 = v1.w;
            } else {
                float4 v0 = *(const float4*)&Y[rrow * YP + k0];
                float4 v1 = *(const float4*)&Y[rrow * YP + k0 + 4];
                float4 s0 = *(const float4*)&scs[k0], s1 = *(const float4*)&scs[k0 + 4];
                float4 t0 = *(const float4*)&shs[k0], t1 = *(const float4*)&shs[k0 + 4];
                f0 = fmaxf(fmaf(v0.x, s0.x, t0.x), 0.f); f1 = fmaxf(fmaf(v0.y, s0.y, t0.y), 0.f);
                f2 = fmaxf(fmaf(v0.z, s0.z, t0.z), 0.f); f3 = fmaxf(fmaf(v0.w, s0.w, t0.w), 0.f);
                f4 = fmaxf(fmaf(v1.x, s1.x, t1.x), 0.f); f5 = fmaxf(fmaf(v1.y, s1.y, t1.y), 0.f);
                f6 = fmaxf(fmaf(v1.z, s1.z, t1.z), 0.f); f7 = fmaxf(fmaf(v1.w, s1.w, t1.w), 0.f);
            }
            unsigned h0, h1, h2, h3, l0, l1, l2, l3;
            split2(f0, f1, h0, l0); split2(f2, f3, h1, l1);
            split2(f4, f5, h2, l2); split2(f6, f7, h3, l3);
            bf16x8 ah = __builtin_bit_cast(bf16x8, make_uint4(h0, h1, h2, h3));
            bf16x8 al = __builtin_bit_cast(bf16x8, make_uint4(l0, l1, l2, l3));
#pragma unroll
            for (int c = 0; c < 8; c++) {
                size_t widx = (size_t)(c * 16 + nl) * HD + k0;
                bf16x8 bh = *(const bf16x8*)(wh + widx);
                bf16x8 bl = *(const bf16x8*)(wl + widx);
                acc[c] = __builtin_amdgcn_mfma_f32_16x16x32_bf16(ah, bh, acc[c], 0, 0, 0);
                acc[c] = __builtin_amdgcn_mfma_f32_16x16x32_bf16(al, bh, acc[c], 0, 0, 0);
                acc[c] = __builtin_amdgcn_mfma_f32_16x16x32_bf16(ah, bl, acc[c], 0, 0, 0);
            }
        }
        __syncthreads();  // everyone done reading Y/scs of previous layer
        if (t < 128) { S[t] = 0.f; Q[t] = 0.f; }
        __syncthreads();
        int baserow = w * 16 + quad * 4;
#pragma unroll
        for (int c = 0; c < 8; c++) {
            int col = c * 16 + nl;
            f32x4 v = acc[c];
            float s = 0.f, qq = 0.f;
#pragma unroll
            for (int r = 0; r < 4; r++) {
                float val = v[r];
                Y[(baserow + r) * YP + col] = val;
                s += val;
                qq += val * val;
            }
            s += __shfl_xor(s, 16, 64);  s += __shfl_xor(s, 32, 64);
            qq += __shfl_xor(qq, 16, 64); qq += __shfl_xor(qq, 32, 64);
            if (quad == 0) {
                atomicAdd(&S[col], s);
                atomicAdd(&Q[col], qq);
            }
        }
        __syncthreads();
        if (t < 128) bn_to_scale(S, Q, gs[L], bs[L], 1.f / NG, t, scs, shs);
        __syncthreads();
    }
    // final: out[g] = sum_c relu(Y[g][c]*sc+sh) * finW[c]
    int g = t >> 2, p = t & 3;
    float s = 0.f;
    for (int c = p * 32; c < p * 32 + 32; c++) {
        float v = fmaxf(fmaf(Y[g * YP + c], scs[c], shs[c]), 0.f);
        s += v * finW[c];
    }
    s += __shfl_down(s, 2, 64);
    s += __shfl_down(s, 1, 64);
    if (p == 0) out[g] = s;
}

extern "C" void kernel_launch(void* const* d_in, const int* in_sizes, int n_in,
                              void* d_out, int out_size, void* d_ws, size_t ws_size,
                              hipStream_t stream) {
    const int* x_ids = (const int*)d_in[0];
    const int* edge_index = (const int*)d_in[1];
    const int* batch = (const int*)d_in[2];
    const int* edge_attr = (const int*)d_in[3];
    const float* node_emb = (const float*)d_in[4];
    const float* edge_emb = (const float*)d_in[5];
    const float* eps = (const float*)d_in[6];
    const float* init_W1 = (const float*)d_in[7];
    const float* init_b1 = (const float*)d_in[8];
    const float* init_g1 = (const float*)d_in[9];
    const float* init_be1 = (const float*)d_in[10];
    const float* init_W2 = (const float*)d_in[11];
    const float* init_b2 = (const float*)d_in[12];
    const float* init_g2 = (const float*)d_in[13];
    const float* init_be2 = (const float*)d_in[14];
    const float* mp_W1 = (const float*)d_in[15];
    const float* mp_g1 = (const float*)d_in[16];
    const float* mp_be1 = (const float*)d_in[17];
    const float* mp_W2 = (const float*)d_in[18];
    const float* mp_g2 = (const float*)d_in[19];
    const float* mp_be2 = (const float*)d_in[20];
    const float* l1_W1 = (const float*)d_in[21];
    const float* l1_g1 = (const float*)d_in[22];
    const float* l1_b1 = (const float*)d_in[23];
    const float* l1_W2 = (const float*)d_in[24];
    const float* l1_g2 = (const float*)d_in[25];
    const float* l1_b2 = (const float*)d_in[26];
    const float* l2_W1 = (const float*)d_in[27];
    const float* l2_g1 = (const float*)d_in[28];
    const float* l2_b1 = (const float*)d_in[29];
    const float* l2_W2 = (const float*)d_in[30];
    const float* l2_g2 = (const float*)d_in[31];
    const float* l2_b2 = (const float*)d_in[32];
    const float* fin_W = (const float*)d_in[33];

    const int* e_src = edge_index;
    const int* e_dst = edge_index + NE;

    // workspace layout
    float* ws = (float*)d_ws;
    float* X = ws;                                   // NN*HD fp32
    float* Bbuf = X + (size_t)NN * HD;               // NN*HD fp32 (H1)
    unsigned short* Ah = (unsigned short*)(Bbuf + (size_t)NN * HD);  // NN*HD bf16
    unsigned short* Al = Ah + (size_t)NN * HD;
    float* Gp = (float*)(Al + (size_t)NN * HD);      // NG*HD fp32
    float* SQ = Gp + NG * HD;                        // 10 stages x 256 floats
    int* rowptr = (int*)(SQ + 2560);                 // 50001 -> pad 50048
    int* cursor = rowptr + 50048;
    int* deg = cursor + 50048;
    int* blockSum = deg + 50048;                     // 64
    int* blockOff = blockSum + 64;                   // 64
    unsigned* csr = (unsigned*)(blockOff + 64);      // NE
    unsigned short* Wh = (unsigned short*)(csr + NE);  // 229376 bf16
    unsigned short* Wl = Wh + 229376;

    hipMemsetAsync(deg, 0, NN * sizeof(int), stream);
    hipMemsetAsync(SQ, 0, 2560 * sizeof(float), stream);
    hipMemsetAsync(Gp, 0, NG * HD * sizeof(float), stream);

    const int SCAN_BLOCKS = (NN + 1023) / 1024;  // 49
    embed_kernel<<<(NN * 32) / 256, 256, 0, stream>>>(x_ids, node_emb, X);
    cvtw_kernel<<<896, 256, 0, stream>>>(init_W1, init_W2, mp_W1, mp_W2,
                                         l1_W1, l1_W2, l2_W1, l2_W2, Wh, Wl);
    hist_kernel<<<(NE + 255) / 256, 256, 0, stream>>>(e_dst, deg);
    scan1_kernel<<<SCAN_BLOCKS, 1024, 0, stream>>>(deg, rowptr, blockSum);
    scan2_kernel<<<1, 64, 0, stream>>>(blockSum, blockOff, rowptr, SCAN_BLOCKS);
    scan3_kernel<<<SCAN_BLOCKS, 1024, 0, stream>>>(rowptr, cursor, blockOff);
    scatter_kernel<<<(NE + 255) / 256, 256, 0, stream>>>(e_src, e_dst, edge_attr, cursor, csr);

    const int mfma_grid = (NN + 127) / 128;  // 391
    for (int i = 0; i <= NL; i++) {
        // weight segments: mm1: i==0 -> 0 else 2+(i-1); mm2: i==0 -> 1 else 6+(i-1)
        const unsigned short* Wh1 = Wh + (size_t)(i == 0 ? 0 : 2 + (i - 1)) * 16384;
        const unsigned short* Wl1 = Wl + (size_t)(i == 0 ? 0 : 2 + (i - 1)) * 16384;
        const unsigned short* Wh2 = Wh + (size_t)(i == 0 ? 1 : 6 + (i - 1)) * 16384;
        const unsigned short* Wl2 = Wl + (size_t)(i == 0 ? 1 : 6 + (i - 1)) * 16384;
        const float* b1 = (i == 0) ? init_b1 : nullptr;
        const float* b2 = (i == 0) ? init_b2 : nullptr;
        const float* g1 = (i == 0) ? init_g1 : mp_g1 + (size_t)(i - 1) * HD;
        const float* be1 = (i == 0) ? init_be1 : mp_be1 + (size_t)(i - 1) * HD;
        // conv act params: previous layer's second BN
        const float* gp = (i == 1) ? init_g2 : mp_g2 + (size_t)(i - 2) * HD;
        const float* bp = (i == 1) ? init_be2 : mp_be2 + (size_t)(i - 2) * HD;
        float* Sprev = SQ + (size_t)(2 * i - 1) * 256;        // stage 2i-1 (valid for i>=1)
        float* S1 = SQ + (size_t)(2 * i) * 256;               // mm1 stats out
        float* S2 = SQ + (size_t)(2 * i + 1) * 256;           // mm2 stats out

        conv_kernel<<<(NN + 3) / 4, 256, 0, stream>>>(
            X, rowptr, csr, edge_emb, eps, i,
            (i > 0) ? Sprev : nullptr, (i > 0) ? Sprev + 128 : nullptr,
            (i > 0) ? gp : nullptr, (i > 0) ? bp : nullptr, (i > 0) ? 1 : 0, Ah, Al);
        mm_mfma_pre<<<mfma_grid, 256, 0, stream>>>(Ah, Al, Wh1, Wl1, b1, Bbuf, S1, S1 + 128);
        mm_mfma_act<<<mfma_grid, 256, 0, stream>>>(Bbuf, Wh2, Wl2, b2, S1, S1 + 128, g1, be1,
                                                   X, S2, S2 + 128);
    }

    float* Slast = SQ + 9 * 256;
    readout_kernel<<<(NN + 255) / 256, 256, 0, stream>>>(
        X, batch, Slast, Slast + 128, mp_g2 + 3 * HD, mp_be2 + 3 * HD, Gp);

    head_kernel<<<1, 512, 0, stream>>>(Gp, Wh + (size_t)10 * 16384, Wl + (size_t)10 * 16384,
                                       l1_g1, l1_b1, l1_g2, l1_b2,
                                       l2_g1, l2_b1, l2_g2, l2_b2,
                                       fin_W, (float*)d_out);
}